// Round 5
// baseline (198.103 us; speedup 1.0000x reference)
//
#include <hip/hip_runtime.h>
#include <hip/hip_bf16.h>
#include <hip/hip_fp16.h>
#include <math.h>

#define B_  8
#define N_  1025
#define C_  512
#define H_  8
#define HD_ 64
#define M_  (B_ * N_)   // 8200
#define VCS 2560        // shorts per vtc chunk-block: 64 dims * 40 (32 keys + 8 pad)
#define VST 36          // vtc chunk-blocks per bh (33 used)
#define BW_ 1088        // bigtab cols (17 x 64-key tiles)

typedef __attribute__((ext_vector_type(8))) short short8;
typedef __attribute__((ext_vector_type(4))) float f32x4;
typedef __attribute__((ext_vector_type(4))) unsigned short us4;

__device__ inline unsigned short bf16u(float x) {
    __hip_bfloat16 t = __float2bfloat16(x);
    return *(unsigned short*)&t;
}
__device__ inline float fexp2(float x) {   // 2^x via v_exp_f32
    float r;
    asm("v_exp_f32 %0, %1" : "=v"(r) : "v"(x));
    return r;
}
__device__ inline float h2f(unsigned short u) {
    __half_raw hr; hr.x = u;
    return __half2float(__half(hr));
}
__device__ inline void load_lds16(const void* g, void* l) {
    __builtin_amdgcn_global_load_lds(
        (const __attribute__((address_space(1))) unsigned int*)g,
        (__attribute__((address_space(3))) unsigned int*)l, 16, 0, 0);
}

// ---------------------------------------------------------------------------
// Fused prep:
//   blocks [0,256): bigtab expansion (256-entry sin/cos table computed once
//     per block, then 32-FMA evals). bigtab now 1088 cols wide (17 x 64-key
//     tiles); c>1024 -> -60000 masks the key-clamped tail.
//   blocks [256, ...): f32 -> bf16 casts of x / qkv_w / proj_w.
// ---------------------------------------------------------------------------
#define PER_ ((size_t)B_ * H_ * N_ * HD_)      // 4,198,400
#define SZ_QKVW (3 * C_ * C_)
#define SZ_PRJW (C_ * C_)
#define CAST_BLKS ((4198400 + 786432 + 262144) / 4 / 256)   // 5124
#define EXP_BLKS 256

__global__ void prep_kernel(const float* __restrict__ x,
                            const float* __restrict__ qkv_w,
                            const float* __restrict__ proj_w,
                            const float* __restrict__ wg_w,
                            const float* __restrict__ wg_b,
                            unsigned short* __restrict__ xb,
                            unsigned short* __restrict__ wqkvb,
                            unsigned short* __restrict__ wprjb,
                            unsigned short* __restrict__ big) {
    __shared__ float tl[1024];
    __shared__ float sT[256], cT[256];
    int blk = blockIdx.x;
    int tid = threadIdx.x;
    if (blk < EXP_BLKS) {
        int h = blk >> 5, rs = blk & 31;
        const float* w = wg_w + h * 64;
        if (tid < 256) {
            const float fr[8] = {1.0f, 0.421696503f, 0.177827941f, 0.074989421f,
                                 0.031622777f, 0.013335214f, 0.005623413f, 0.002371374f};
            int a = tid >> 3, k = tid & 7;
            float dxv = logf(fmaxf((float)a * (1.0f / 33.0f), 0.001f));
            float ang = 100.0f * dxv * fr[k];
            sT[tid] = sinf(ang);
            cT[tid] = cosf(ang);
        }
        __syncthreads();
        float wb = wg_b[h];
        float wtail = 0.f;
#pragma unroll
        for (int k = 0; k < 8; k++) wtail += w[48 + k] + w[56 + k];
#pragma unroll 1
        for (int e = tid; e < 1024; e += 256) {
            int a = e >> 5, b = e & 31;
            float acc = wb + wtail;
#pragma unroll
            for (int k = 0; k < 8; k++) {
                acc += w[k]      * sT[a * 8 + k];
                acc += w[8 + k]  * sT[b * 8 + k];
                acc += w[32 + k] * cT[a * 8 + k];
                acc += w[40 + k] * cT[b * 8 + k];
            }
            tl[e] = log2f(fmaxf(fmaxf(acc, 0.0f), 1e-6f));
        }
        __syncthreads();
        int rbase = rs * 36;
#pragma unroll 1
        for (int e8 = tid; e8 < 36 * 136; e8 += 256) {
            int rr = e8 / 136;
            int cg = e8 - rr * 136;
            int r = rbase + rr;
            int c0 = cg * 8;
            int i = min(r, 1024) - 1;
            int ix = i >> 5, iy = i & 31;
            unsigned short o8[8];
#pragma unroll
            for (int e = 0; e < 8; e++) {
                int c = c0 + e;
                float v;
                if (r == 0 || c == 0) v = 0.f;
                else if (c > 1024)    v = -60000.f;
                else {
                    int j = c - 1;
                    int da = __sad(ix, j >> 5, 0u);
                    int db = __sad(iy, j & 31, 0u);
                    v = tl[da * 32 + db];
                }
                __half hv = __float2half(v);
                o8[e] = *(unsigned short*)&hv;
            }
            *(short8*)(big + ((size_t)h * 1152 + r) * BW_ + c0) = *(short8*)o8;
        }
        return;
    }
    long i4 = ((long)(blk - EXP_BLKS) * 256 + tid) * 4;
    const float* src;
    unsigned short* dst;
    long off;
    if (i4 < (long)PER_)                    { src = x;      dst = xb;    off = i4; }
    else if (i4 < (long)PER_ + SZ_QKVW)     { src = qkv_w;  dst = wqkvb; off = i4 - PER_; }
    else                                    { src = proj_w; dst = wprjb; off = i4 - PER_ - SZ_QKVW; }
    float4 v = *(const float4*)(src + off);
    ushort4 p;
    p.x = bf16u(v.x); p.y = bf16u(v.y); p.z = bf16u(v.z); p.w = bf16u(v.w);
    *(ushort4*)(dst + off) = p;
}

// ---------------------------------------------------------------------------
// MFMA GEMM, 128x128 tile, BK=32, 4 waves, 2-phase double-buffered.
// q scaled by 0.125*log2(e). v scattered with key-slot permutation
//   sigma(k) = ((k>>2)&3)*8 + ((k>>4)<<2) + (k&3), 40-stride dim rows.
// ---------------------------------------------------------------------------
#define GK 512

__global__ __launch_bounds__(256) void gemm_qkv_mfma(
        const unsigned short* __restrict__ A, const unsigned short* __restrict__ W,
        unsigned short* __restrict__ qb, unsigned short* __restrict__ kb,
        unsigned short* __restrict__ vtc) {
    __shared__ __align__(16) unsigned short As[2][128 * 32];
    __shared__ __align__(16) unsigned short Bs[2][128 * 32];
    int tid = threadIdx.x;
    int w = tid >> 6, lane = tid & 63;
    int quad = lane >> 4, l16 = lane & 15;
    int m0 = blockIdx.y * 128;
    int n0 = blockIdx.x * 128;
    int wr = (w >> 1) * 64, wc = (w & 1) * 64;

    int c0 = tid, c1 = tid + 256;
    int a_r0 = min(m0 + (c0 >> 2), M_ - 1), a_c0 = (c0 & 3) * 8;
    int a_r1 = min(m0 + (c1 >> 2), M_ - 1), a_c1 = (c1 & 3) * 8;
    int b_r0 = n0 + (c0 >> 2), b_r1 = n0 + (c1 >> 2);

    int which = n0 >> 9;                       // 0=q 1=k 2=v
    int h = ((n0 + wc) >> 6) & 7;

    f32x4 acc[4][4];
    const f32x4 zero4 = {0.f, 0.f, 0.f, 0.f};
#pragma unroll
    for (int mi = 0; mi < 4; mi++)
#pragma unroll
        for (int ni = 0; ni < 4; ni++) acc[mi][ni] = zero4;

    auto stage = [&](int k0, int buf) {
        load_lds16(A + (size_t)a_r0 * GK + k0 + a_c0, &As[buf][w * 512]);
        load_lds16(A + (size_t)a_r1 * GK + k0 + a_c1, &As[buf][2048 + w * 512]);
        load_lds16(W + (size_t)b_r0 * GK + k0 + a_c0, &Bs[buf][w * 512]);
        load_lds16(W + (size_t)b_r1 * GK + k0 + a_c1, &Bs[buf][2048 + w * 512]);
    };
    stage(0, 0);

    for (int k0 = 0; k0 < GK; k0 += 32) {
        int buf = (k0 >> 5) & 1;
        __syncthreads();                 // buf staged (vmcnt drained); buf^1 free
        if (k0 + 32 < GK) stage(k0 + 32, buf ^ 1);
        short8 af[4], bf[4];
#pragma unroll
        for (int mi = 0; mi < 4; mi++)
            af[mi] = *(const short8*)&As[buf][(wr + mi * 16 + l16) * 32 + quad * 8];
#pragma unroll
        for (int ni = 0; ni < 4; ni++)
            bf[ni] = *(const short8*)&Bs[buf][(wc + ni * 16 + l16) * 32 + quad * 8];
#pragma unroll
        for (int mi = 0; mi < 4; mi++)
#pragma unroll
            for (int ni = 0; ni < 4; ni++)
                acc[mi][ni] = __builtin_amdgcn_mfma_f32_16x16x32_bf16(
                    bf[ni], af[mi], acc[mi][ni], 0, 0, 0);
    }

    if (which < 2) {
        unsigned short* dst = (which == 0) ? qb : kb;
        float sc = (which == 0) ? 0.18033688f : 1.0f;   // 0.125 * log2(e)
#pragma unroll
        for (int mi = 0; mi < 4; mi++) {
            int m = m0 + wr + mi * 16 + l16;
            if (m < M_) {
                int bb = m / N_;
                int i  = m - bb * N_;
                unsigned short* row = dst + ((size_t)(bb * H_ + h) * N_ + i) * HD_;
#pragma unroll
                for (int ni = 0; ni < 4; ni++) {
                    ushort4 pk;
                    pk.x = bf16u(acc[mi][ni][0] * sc);
                    pk.y = bf16u(acc[mi][ni][1] * sc);
                    pk.z = bf16u(acc[mi][ni][2] * sc);
                    pk.w = bf16u(acc[mi][ni][3] * sc);
                    *(ushort4*)(row + ni * 16 + quad * 4) = pk;
                }
            }
        }
    } else {
#pragma unroll
        for (int mi = 0; mi < 4; mi++) {
            int m = m0 + wr + mi * 16 + l16;
            if (m < M_) {
                int bb = m / N_;
                int i  = m - bb * N_;
                int ch = i >> 5, key = i & 31;
                int slot = ((key >> 2) & 3) * 8 + ((key >> 4) << 2) + (key & 3);
                unsigned short* base = vtc + ((size_t)(bb * H_ + h) * VST + ch) * VCS + slot;
#pragma unroll
                for (int ni = 0; ni < 4; ni++)
#pragma unroll
                    for (int reg = 0; reg < 4; reg++)
                        base[(ni * 16 + quad * 4 + reg) * 40] = bf16u(acc[mi][ni][reg]);
            }
        }
    }
}

__global__ __launch_bounds__(256) void gemm_proj_mfma(
        const unsigned short* __restrict__ A, const unsigned short* __restrict__ W,
        const float* __restrict__ bias, float* __restrict__ out) {
    __shared__ __align__(16) unsigned short As[2][128 * 32];
    __shared__ __align__(16) unsigned short Bs[2][128 * 32];
    int tid = threadIdx.x;
    int w = tid >> 6, lane = tid & 63;
    int quad = lane >> 4, l16 = lane & 15;
    int m0 = blockIdx.y * 128;
    int n0 = blockIdx.x * 128;
    int wr = (w >> 1) * 64, wc = (w & 1) * 64;

    int c0 = tid, c1 = tid + 256;
    int a_r0 = min(m0 + (c0 >> 2), M_ - 1), a_c0 = (c0 & 3) * 8;
    int a_r1 = min(m0 + (c1 >> 2), M_ - 1), a_c1 = (c1 & 3) * 8;
    int b_r0 = n0 + (c0 >> 2), b_r1 = n0 + (c1 >> 2);

    f32x4 acc[4][4];
    const f32x4 zero4 = {0.f, 0.f, 0.f, 0.f};
#pragma unroll
    for (int mi = 0; mi < 4; mi++)
#pragma unroll
        for (int ni = 0; ni < 4; ni++) acc[mi][ni] = zero4;

    auto stage = [&](int k0, int buf) {
        load_lds16(A + (size_t)a_r0 * GK + k0 + a_c0, &As[buf][w * 512]);
        load_lds16(A + (size_t)a_r1 * GK + k0 + a_c1, &As[buf][2048 + w * 512]);
        load_lds16(W + (size_t)b_r0 * GK + k0 + a_c0, &Bs[buf][w * 512]);
        load_lds16(W + (size_t)b_r1 * GK + k0 + a_c1, &Bs[buf][2048 + w * 512]);
    };
    stage(0, 0);

    for (int k0 = 0; k0 < GK; k0 += 32) {
        int buf = (k0 >> 5) & 1;
        __syncthreads();
        if (k0 + 32 < GK) stage(k0 + 32, buf ^ 1);
        short8 af[4], bf[4];
#pragma unroll
        for (int mi = 0; mi < 4; mi++)
            af[mi] = *(const short8*)&As[buf][(wr + mi * 16 + l16) * 32 + quad * 8];
#pragma unroll
        for (int ni = 0; ni < 4; ni++)
            bf[ni] = *(const short8*)&Bs[buf][(wc + ni * 16 + l16) * 32 + quad * 8];
#pragma unroll
        for (int mi = 0; mi < 4; mi++)
#pragma unroll
            for (int ni = 0; ni < 4; ni++)
                acc[mi][ni] = __builtin_amdgcn_mfma_f32_16x16x32_bf16(
                    af[mi], bf[ni], acc[mi][ni], 0, 0, 0);
    }

    float bvals[4];
#pragma unroll
    for (int ni = 0; ni < 4; ni++) bvals[ni] = bias[n0 + wc + ni * 16 + l16];
#pragma unroll
    for (int mi = 0; mi < 4; mi++)
#pragma unroll
        for (int reg = 0; reg < 4; reg++) {
            int m = m0 + wr + mi * 16 + quad * 4 + reg;
            if (m < M_) {
                float* row = out + (size_t)m * C_ + n0 + wc;
#pragma unroll
                for (int ni = 0; ni < 4; ni++)
                    row[ni * 16 + l16] = acc[mi][ni][reg] + bvals[ni];
            }
        }
}

// ---------------------------------------------------------------------------
// FUSED attention v9: 3-WAVE BLOCKS x 3 BLOCKS/CU. R4 counters: no pipe >27%
// at Occupancy 21% -> grid-capped at 1 lockstep 9-wave block/CU (9 waves on
// 4 SIMDs = 3/2/2/2, straggler at every barrier). Now: 64-key tiles shrink
// LDS to 36KB (Ks 2x8K + Vs 2x10K) -> 3 independent blocks co-resident per
// CU with desynced barriers (m114 implicit overlap); each barrier syncs only
// 3 waves. 32-rows/wave sharing and per-key read ratios unchanged. Grid
// 704 = 64bh x 11mt x 96 rows, lin&7 = h keeps XCD L2 co-location. 17 tiles
// of 64 keys; keys 1056..1087 masked by bigtab -60000 (BW_=1088), V-chunk
// index clamped to 32.
// ---------------------------------------------------------------------------
#define RT_ 96    // rows per block (3 waves x 32)
#define NT_ 17    // 64-key tiles

__global__ __launch_bounds__(192, 3) void attn_fused(
        const unsigned short* __restrict__ qg,
        const unsigned short* __restrict__ kg,
        const unsigned short* __restrict__ vtc,
        const unsigned short* __restrict__ bigtab,
        unsigned short* __restrict__ ob) {
    // Ks chunk ch = ct*128 + oct*16 + k16 holds K[key=t*64+ct*16+k16][oct*8..+8]
    // Vs: 2 ks-blocks of [64 dims][40 slots] (32 keys sigma-permuted + 8 pad)
    __shared__ __align__(16) unsigned short Ks[2][4096];   // 16 KB
    __shared__ __align__(16) unsigned short Vs[2][5120];   // 20 KB

    int tid = threadIdx.x;
    int w = tid >> 6, lane = tid & 63;
    int quad = lane >> 4, l16 = lane & 15;

    int lin = blockIdx.x;            // 704 blocks
    int bh = lin & 63;               // lin%8 = bh&7 = h -> XCD co-location
    int mt = lin >> 6;               // 0..10
    int b = bh >> 3, h = bh & 7;

    const unsigned short* qp = qg + (size_t)bh * N_ * HD_;
    const unsigned short* kp = kg + (size_t)bh * N_ * HD_;
    const unsigned short* vp = vtc + (size_t)bh * VST * VCS;

    int qrA = mt * RT_ + w * 32 + l16;           // qgrp A rows (A-layout, l16)
    const unsigned short* btA = bigtab + ((size_t)h * 1152 + qrA) * BW_ + quad * 4;
    const unsigned short* btB = btA + (size_t)16 * BW_;

    // Q fragments for both query groups
    short8 qfA[2], qfB[2];
    {
        int rowA = min(qrA, N_ - 1);
        int rowB = min(qrA + 16, N_ - 1);
        qfA[0] = *(const short8*)(qp + (size_t)rowA * HD_ + quad * 8);
        qfA[1] = *(const short8*)(qp + (size_t)rowA * HD_ + 32 + quad * 8);
        qfB[0] = *(const short8*)(qp + (size_t)rowB * HD_ + quad * 8);
        qfB[1] = *(const short8*)(qp + (size_t)rowB * HD_ + 32 + quad * 8);
    }

    f32x4 oA[4], oB[4], lA, lB;
    const f32x4 zero4 = {0.f, 0.f, 0.f, 0.f};
#pragma unroll
    for (int g2 = 0; g2 < 4; g2++) { oA[g2] = zero4; oB[g2] = zero4; }
    lA = zero4; lB = zero4;
    short8 ones;
    {
        short one_bf = (short)0x3F80;
#pragma unroll
        for (int j = 0; j < 8; j++) ones[j] = one_bf;
    }

    // staging: 18 64-chunk blocks (8 K + 10 V), 6 per wave. Lane-linear.
    auto stage = [&](int t, int buf) {
#pragma unroll
        for (int r2 = 0; r2 < 6; r2++) {
            int cb = w * 6 + r2;                 // 0..17, uniform per wave
            if (cb < 8) {
                int ch = cb * 64 + lane;
                int ct = ch >> 7, rem = ch & 127;
                int oct = rem >> 4, k16 = rem & 15;
                int key = min(t * 64 + ct * 16 + k16, N_ - 1);
                load_lds16(kp + (size_t)key * HD_ + oct * 8, &Ks[buf][cb * 512]);
            } else {
                int vb = cb - 8;                 // 0..9
                int vc = (vb >= 5) ? 1 : 0;
                int off = (vb - vc * 5) * 512;
                int gidx = min(t * 2 + vc, 32);  // clamp tail to chunk 32
                load_lds16(vp + (size_t)gidx * VCS + off + lane * 8,
                           &Vs[buf][vb * 512]);
            }
        }
    };

    // bias: qgrp A prefetched one tile ahead (4 us4); qgrp B loaded in-tile.
    us4 bAc[4], bAn[4];
#pragma unroll
    for (int i = 0; i < 4; i++)
        bAn[i] = *(const us4*)(btA + (i >> 1) * 32 + (i & 1) * 16);
    stage(0, 0);

#pragma unroll 1
    for (int t = 0; t < NT_; t++) {
        int buf = t & 1;
        __syncthreads();                  // Ks/Vs[buf] ready (vmcnt drained)

#pragma unroll
        for (int i = 0; i < 4; i++) bAc[i] = bAn[i];
        us4 bB[4];
        {
            const unsigned short* btp = btB + t * 64;
#pragma unroll
            for (int i = 0; i < 4; i++)
                bB[i] = *(const us4*)(btp + (i >> 1) * 32 + (i & 1) * 16);
        }
        if (t < NT_ - 1) {
            const unsigned short* btp = btA + (t + 1) * 64;
#pragma unroll
            for (int i = 0; i < 4; i++)
                bAn[i] = *(const us4*)(btp + (i >> 1) * 32 + (i & 1) * 16);
            stage(t + 1, buf ^ 1);
        }

        // ---- per 32-key step: QK (both grps, kf shared), softmax+PV A, B ----
#pragma unroll
        for (int ks = 0; ks < 2; ks++) {
            f32x4 sA[2], sB[2];
#pragma unroll
            for (int ctl = 0; ctl < 2; ctl++) {
                int ct = ks * 2 + ctl;
                short8 kf0 = *(const short8*)&Ks[buf][(ct * 128 + quad * 16 + l16) * 8];
                short8 kf1 = *(const short8*)&Ks[buf][(ct * 128 + (4 + quad) * 16 + l16) * 8];
                sA[ctl] = __builtin_amdgcn_mfma_f32_16x16x32_bf16(kf0, qfA[0], zero4, 0, 0, 0);
                sA[ctl] = __builtin_amdgcn_mfma_f32_16x16x32_bf16(kf1, qfA[1], sA[ctl], 0, 0, 0);
                sB[ctl] = __builtin_amdgcn_mfma_f32_16x16x32_bf16(kf0, qfB[0], zero4, 0, 0, 0);
                sB[ctl] = __builtin_amdgcn_mfma_f32_16x16x32_bf16(kf1, qfB[1], sB[ctl], 0, 0, 0);
            }
            // V fragments read once, shared by both query groups
            const unsigned short* vcp = &Vs[buf][ks * 2560 + quad * 8];
            short8 vf[4];
#pragma unroll
            for (int g2 = 0; g2 < 4; g2++)
                vf[g2] = *(const short8*)(vcp + (g2 * 16 + l16) * 40);

            // softmax + PV, group A
            short8 pfA;
#pragma unroll
            for (int e = 0; e < 8; e++) {
                int par = e >> 2, r = e & 3;
                float bia = h2f(bAc[ks * 2 + par][r]);
                pfA[e] = (short)bf16u(fexp2(sA[par][r] + bia));
            }
            __builtin_amdgcn_s_setprio(1);
#pragma unroll
            for (int g2 = 0; g2 < 4; g2++)
                oA[g2] = __builtin_amdgcn_mfma_f32_16x16x32_bf16(pfA, vf[g2], oA[g2], 0, 0, 0);
            lA = __builtin_amdgcn_mfma_f32_16x16x32_bf16(pfA, ones, lA, 0, 0, 0);
            __builtin_amdgcn_s_setprio(0);

            // softmax + PV, group B
            short8 pfB;
#pragma unroll
            for (int e = 0; e < 8; e++) {
                int par = e >> 2, r = e & 3;
                float bia = h2f(bB[ks * 2 + par][r]);
                pfB[e] = (short)bf16u(fexp2(sB[par][r] + bia));
            }
            __builtin_amdgcn_s_setprio(1);
#pragma unroll
            for (int g2 = 0; g2 < 4; g2++)
                oB[g2] = __builtin_amdgcn_mfma_f32_16x16x32_bf16(pfB, vf[g2], oB[g2], 0, 0, 0);
            lB = __builtin_amdgcn_mfma_f32_16x16x32_bf16(pfB, ones, lB, 0, 0, 0);
            __builtin_amdgcn_s_setprio(0);
        }
    }

    // ---- epilogue: o/l -> ob bf16 (C-layout rows = query; pad rows skip) ----
#pragma unroll
    for (int grp = 0; grp < 2; grp++) {
        int rbase = mt * RT_ + w * 32 + grp * 16 + quad * 4;
        const f32x4* oX = grp ? oB : oA;
        const f32x4& lX = grp ? lB : lA;
#pragma unroll
        for (int reg = 0; reg < 4; reg++) {
            int r = rbase + reg;
            if (r < N_) {
                float inv = 1.0f / lX[reg];
                unsigned short* orow = ob + ((size_t)b * N_ + r) * C_ + h * HD_ + l16;
#pragma unroll
                for (int g2 = 0; g2 < 4; g2++)
                    orow[g2 * 16] = bf16u(oX[g2][reg] * inv);
            }
        }
    }
}

// ---------------------------------------------------------------------------
extern "C" void kernel_launch(void* const* d_in, const int* in_sizes, int n_in,
                              void* d_out, int out_size, void* d_ws, size_t ws_size,
                              hipStream_t stream) {
    const float* x      = (const float*)d_in[0];
    const float* qkv_w  = (const float*)d_in[1];
    const float* proj_w = (const float*)d_in[2];
    const float* proj_b = (const float*)d_in[3];
    const float* wg_w   = (const float*)d_in[4];
    const float* wg_b   = (const float*)d_in[5];
    float* out = (float*)d_out;

    const size_t per = PER_;
    char* ws = (char*)d_ws;
    unsigned short* bigtab = (unsigned short*)ws;                   // 20,054,016 B
    unsigned short* xb     = bigtab + (size_t)8 * 1152 * BW_;       //  8,396,800 B
    unsigned short* wqkvb  = xb + per;                              //  1,572,864 B
    unsigned short* wprjb  = wqkvb + (size_t)SZ_QKVW;               //    524,288 B
    unsigned short* qb     = wprjb + (size_t)SZ_PRJW;               //  8,396,800 B
    unsigned short* kb     = qb + per;                              //  8,396,800 B
    unsigned short* vtc    = kb + per;                              // 11,796,480 B
    unsigned short* ob     = vtc + (size_t)64 * VST * VCS;          //  8,396,800 B

    prep_kernel<<<EXP_BLKS + CAST_BLKS, 256, 0, stream>>>(x, qkv_w, proj_w, wg_w, wg_b,
                                                          xb, wqkvb, wprjb, bigtab);
    gemm_qkv_mfma<<<dim3(12, 65), 256, 0, stream>>>(xb, wqkvb, qb, kb, vtc);
    attn_fused<<<704, 192, 0, stream>>>(qb, kb, vtc, bigtab, ob);
    gemm_proj_mfma<<<dim3(4, 65), 256, 0, stream>>>(ob, wprjb, proj_b, out);
}

// Round 6
// 183.993 us; speedup vs baseline: 1.0767x; 1.0767x over previous
//
#include <hip/hip_runtime.h>
#include <hip/hip_bf16.h>
#include <hip/hip_fp16.h>
#include <math.h>

#define B_  8
#define N_  1025
#define C_  512
#define H_  8
#define HD_ 64
#define M_  (B_ * N_)   // 8200
#define VCS 2560        // shorts per vtc chunk-block: 64 dims * 40 (32 keys + 8 pad)
#define VST 36          // vtc chunk-blocks per bh (33 used)
#define BW_ 1056        // bigtab cols (11 x 96-key tiles)
#define PER_ ((size_t)B_ * H_ * N_ * HD_)      // 4,198,400
#define EXP_BLKS 256
#define GK 512

typedef __attribute__((ext_vector_type(8))) short short8;
typedef __attribute__((ext_vector_type(4))) float f32x4;
typedef __attribute__((ext_vector_type(4))) unsigned short us4;

__device__ inline unsigned short bf16u(float x) {
    __hip_bfloat16 t = __float2bfloat16(x);
    return *(unsigned short*)&t;
}
__device__ inline float fexp2(float x) {   // 2^x via v_exp_f32
    float r;
    asm("v_exp_f32 %0, %1" : "=v"(r) : "v"(x));
    return r;
}
__device__ inline float h2f(unsigned short u) {
    __half_raw hr; hr.x = u;
    return __half2float(__half(hr));
}
__device__ inline void load_lds16(const void* g, void* l) {
    __builtin_amdgcn_global_load_lds(
        (const __attribute__((address_space(1))) unsigned int*)g,
        (__attribute__((address_space(3))) unsigned int*)l, 16, 0, 0);
}
__device__ inline short8 pack8(float4 u0, float4 u1) {
    short8 r;
    r[0] = (short)bf16u(u0.x); r[1] = (short)bf16u(u0.y);
    r[2] = (short)bf16u(u0.z); r[3] = (short)bf16u(u0.w);
    r[4] = (short)bf16u(u1.x); r[5] = (short)bf16u(u1.y);
    r[6] = (short)bf16u(u1.z); r[7] = (short)bf16u(u1.w);
    return r;
}

// ---------------------------------------------------------------------------
// GEMM QKV + bigtab, ONE dispatch (3-dispatch pipeline: this, attn, proj).
//  blocks [0,256): bigtab expansion (per-h MLP table in LDS, fp16 log2 rows;
//    pad row/col-0 = 0, c>1024 = -60000). Consumed only by the NEXT dispatch.
//  blocks [256,1036): 128x128 MFMA gemm, BK=32, f32 inputs reg-staged to bf16
//    LDS (cast pass deleted; T14 order: loads before barrier, writes after
//    MFMA). q scaled 0.125*log2(e); v scattered with sigma key-permutation +
//    40-stride dim rows.
// ---------------------------------------------------------------------------
__global__ __launch_bounds__(256) void gemm_qkv_mfma(
        const float* __restrict__ x, const float* __restrict__ qkv_w,
        const float* __restrict__ wg_w, const float* __restrict__ wg_b,
        unsigned short* __restrict__ qb, unsigned short* __restrict__ kb,
        unsigned short* __restrict__ vtc, unsigned short* __restrict__ big) {
    __shared__ __align__(16) unsigned short As[2][4096];
    __shared__ __align__(16) unsigned short Bs[2][4096];
    int lin = blockIdx.x;
    int tid = threadIdx.x;

    if (lin < EXP_BLKS) {
        float* tl = (float*)&As[0][0];          // 4 KB of the 16 KB As
        float* sT = (float*)&Bs[0][0];
        float* cT = sT + 256;
        int h = lin >> 5, rs = lin & 31;
        const float* w = wg_w + h * 64;
        {
            const float fr[8] = {1.0f, 0.421696503f, 0.177827941f, 0.074989421f,
                                 0.031622777f, 0.013335214f, 0.005623413f, 0.002371374f};
            int a = tid >> 3, k = tid & 7;
            float dxv = logf(fmaxf((float)a * (1.0f / 33.0f), 0.001f));
            float ang = 100.0f * dxv * fr[k];
            sT[tid] = sinf(ang);
            cT[tid] = cosf(ang);
        }
        __syncthreads();
        float wb = wg_b[h];
        float wtail = 0.f;
#pragma unroll
        for (int k = 0; k < 8; k++) wtail += w[48 + k] + w[56 + k];
#pragma unroll 1
        for (int e = tid; e < 1024; e += 256) {
            int a = e >> 5, b = e & 31;
            float acc = wb + wtail;
#pragma unroll
            for (int k = 0; k < 8; k++) {
                acc += w[k]      * sT[a * 8 + k];
                acc += w[8 + k]  * sT[b * 8 + k];
                acc += w[32 + k] * cT[a * 8 + k];
                acc += w[40 + k] * cT[b * 8 + k];
            }
            tl[e] = log2f(fmaxf(fmaxf(acc, 0.0f), 1e-6f));
        }
        __syncthreads();
        int rbase = rs * 36;
#pragma unroll 1
        for (int e8 = tid; e8 < 36 * 132; e8 += 256) {
            int rr = e8 / 132;
            int cg = e8 - rr * 132;
            int r = rbase + rr;
            int c0 = cg * 8;
            int i = min(r, 1024) - 1;
            int ix = i >> 5, iy = i & 31;
            unsigned short o8[8];
#pragma unroll
            for (int e = 0; e < 8; e++) {
                int c = c0 + e;
                float v;
                if (r == 0 || c == 0) v = 0.f;
                else if (c > 1024)    v = -60000.f;
                else {
                    int j = c - 1;
                    int da = __sad(ix, j >> 5, 0u);
                    int db = __sad(iy, j & 31, 0u);
                    v = tl[da * 32 + db];
                }
                __half hv = __float2half(v);
                o8[e] = *(unsigned short*)&hv;
            }
            *(short8*)(big + ((size_t)h * 1152 + r) * BW_ + c0) = *(short8*)o8;
        }
        return;
    }

    int bidx = lin - EXP_BLKS;
    int bx = bidx % 12, by = bidx / 12;        // n-tile 0..11, m-tile 0..64
    int wv = tid >> 6, lane = tid & 63;
    int quad = lane >> 4, l16 = lane & 15;
    int m0 = by * 128, n0 = bx * 128;
    int wr = (wv >> 1) * 64, wc = (wv & 1) * 64;

    int ar0 = min(m0 + (tid >> 2), M_ - 1);
    int ar1 = min(m0 + 64 + (tid >> 2), M_ - 1);
    int br0 = n0 + (tid >> 2), br1 = n0 + 64 + (tid >> 2);
    int ac = (tid & 3) * 8;

    int which = n0 >> 9;                       // 0=q 1=k 2=v
    int h = ((n0 + wc) >> 6) & 7;

    f32x4 acc[4][4];
    const f32x4 zero4 = {0.f, 0.f, 0.f, 0.f};
#pragma unroll
    for (int mi = 0; mi < 4; mi++)
#pragma unroll
        for (int ni = 0; ni < 4; ni++) acc[mi][ni] = zero4;

    float4 ra0, ra1, ra2, ra3, rb0, rb1, rb2, rb3;
    auto loadAll = [&](int k0) {
        const float* pa0 = x + (size_t)ar0 * GK + k0 + ac;
        const float* pa1 = x + (size_t)ar1 * GK + k0 + ac;
        const float* pb0 = qkv_w + (size_t)br0 * GK + k0 + ac;
        const float* pb1 = qkv_w + (size_t)br1 * GK + k0 + ac;
        ra0 = *(const float4*)pa0; ra1 = *(const float4*)(pa0 + 4);
        ra2 = *(const float4*)pa1; ra3 = *(const float4*)(pa1 + 4);
        rb0 = *(const float4*)pb0; rb1 = *(const float4*)(pb0 + 4);
        rb2 = *(const float4*)pb1; rb3 = *(const float4*)(pb1 + 4);
    };
    auto writeAll = [&](int buf) {
        *(short8*)&As[buf][tid * 8]        = pack8(ra0, ra1);
        *(short8*)&As[buf][2048 + tid * 8] = pack8(ra2, ra3);
        *(short8*)&Bs[buf][tid * 8]        = pack8(rb0, rb1);
        *(short8*)&Bs[buf][2048 + tid * 8] = pack8(rb2, rb3);
    };
    loadAll(0);
    writeAll(0);

    for (int k0 = 0; k0 < GK; k0 += 32) {
        int buf = (k0 >> 5) & 1;
        if (k0 + 32 < GK) loadAll(k0 + 32);    // HBM latency hides under barrier+MFMA
        __syncthreads();                       // buf's ds_writes visible
        short8 af[4], bf[4];
#pragma unroll
        for (int mi = 0; mi < 4; mi++)
            af[mi] = *(const short8*)&As[buf][(wr + mi * 16 + l16) * 32 + quad * 8];
#pragma unroll
        for (int ni = 0; ni < 4; ni++)
            bf[ni] = *(const short8*)&Bs[buf][(wc + ni * 16 + l16) * 32 + quad * 8];
#pragma unroll
        for (int mi = 0; mi < 4; mi++)
#pragma unroll
            for (int ni = 0; ni < 4; ni++)
                acc[mi][ni] = __builtin_amdgcn_mfma_f32_16x16x32_bf16(
                    bf[ni], af[mi], acc[mi][ni], 0, 0, 0);
        if (k0 + 32 < GK) writeAll(buf ^ 1);   // cvt+ds_write after MFMA (T14)
    }

    if (which < 2) {
        unsigned short* dst = (which == 0) ? qb : kb;
        float sc = (which == 0) ? 0.18033688f : 1.0f;   // 0.125 * log2(e)
#pragma unroll
        for (int mi = 0; mi < 4; mi++) {
            int m = m0 + wr + mi * 16 + l16;
            if (m < M_) {
                int bb = m / N_;
                int i  = m - bb * N_;
                unsigned short* row = dst + ((size_t)(bb * H_ + h) * N_ + i) * HD_;
#pragma unroll
                for (int ni = 0; ni < 4; ni++) {
                    ushort4 pk;
                    pk.x = bf16u(acc[mi][ni][0] * sc);
                    pk.y = bf16u(acc[mi][ni][1] * sc);
                    pk.z = bf16u(acc[mi][ni][2] * sc);
                    pk.w = bf16u(acc[mi][ni][3] * sc);
                    *(ushort4*)(row + ni * 16 + quad * 4) = pk;
                }
            }
        }
    } else {
#pragma unroll
        for (int mi = 0; mi < 4; mi++) {
            int m = m0 + wr + mi * 16 + l16;
            if (m < M_) {
                int bb = m / N_;
                int i  = m - bb * N_;
                int ch = i >> 5, key = i & 31;
                int slot = ((key >> 2) & 3) * 8 + ((key >> 4) << 2) + (key & 3);
                unsigned short* base = vtc + ((size_t)(bb * H_ + h) * VST + ch) * VCS + slot;
#pragma unroll
                for (int ni = 0; ni < 4; ni++)
#pragma unroll
                    for (int reg = 0; reg < 4; reg++)
                        base[(ni * 16 + quad * 4 + reg) * 40] = bf16u(acc[mi][ni][reg]);
            }
        }
    }
}

// ---------------------------------------------------------------------------
// GEMM proj: A-side (ob, bf16) via global_load_lds; W-side (proj_w, f32)
// reg-staged with on-the-fly bf16 cast (cast pass deleted).
// ---------------------------------------------------------------------------
__global__ __launch_bounds__(256) void gemm_proj_mfma(
        const unsigned short* __restrict__ A, const float* __restrict__ Wf,
        const float* __restrict__ bias, float* __restrict__ out) {
    __shared__ __align__(16) unsigned short As[2][4096];
    __shared__ __align__(16) unsigned short Bs[2][4096];
    int tid = threadIdx.x;
    int w = tid >> 6, lane = tid & 63;
    int quad = lane >> 4, l16 = lane & 15;
    int m0 = blockIdx.y * 128;
    int n0 = blockIdx.x * 128;
    int wr = (w >> 1) * 64, wc = (w & 1) * 64;

    int ar0 = min(m0 + (tid >> 2), M_ - 1);
    int ar1 = min(m0 + 64 + (tid >> 2), M_ - 1);
    int br0 = n0 + (tid >> 2), br1 = n0 + 64 + (tid >> 2);
    int ac = (tid & 3) * 8;

    f32x4 acc[4][4];
    const f32x4 zero4 = {0.f, 0.f, 0.f, 0.f};
#pragma unroll
    for (int mi = 0; mi < 4; mi++)
#pragma unroll
        for (int ni = 0; ni < 4; ni++) acc[mi][ni] = zero4;

    auto stageA = [&](int k0, int buf) {
        load_lds16(A + (size_t)ar0 * GK + k0 + ac, &As[buf][w * 512]);
        load_lds16(A + (size_t)ar1 * GK + k0 + ac, &As[buf][2048 + w * 512]);
    };
    float4 rw0, rw1, rw2, rw3;
    auto loadW = [&](int k0) {
        const float* p0 = Wf + (size_t)br0 * GK + k0 + ac;
        const float* p1 = Wf + (size_t)br1 * GK + k0 + ac;
        rw0 = *(const float4*)p0; rw1 = *(const float4*)(p0 + 4);
        rw2 = *(const float4*)p1; rw3 = *(const float4*)(p1 + 4);
    };
    auto writeW = [&](int buf) {
        *(short8*)&Bs[buf][tid * 8]        = pack8(rw0, rw1);
        *(short8*)&Bs[buf][2048 + tid * 8] = pack8(rw2, rw3);
    };
    stageA(0, 0);
    loadW(0);
    writeW(0);

    for (int k0 = 0; k0 < GK; k0 += 32) {
        int buf = (k0 >> 5) & 1;
        __syncthreads();                 // drains A load_lds + W ds_writes
        if (k0 + 32 < GK) { stageA(k0 + 32, buf ^ 1); loadW(k0 + 32); }
        short8 af[4], bf[4];
#pragma unroll
        for (int mi = 0; mi < 4; mi++)
            af[mi] = *(const short8*)&As[buf][(wr + mi * 16 + l16) * 32 + quad * 8];
#pragma unroll
        for (int ni = 0; ni < 4; ni++)
            bf[ni] = *(const short8*)&Bs[buf][(wc + ni * 16 + l16) * 32 + quad * 8];
#pragma unroll
        for (int mi = 0; mi < 4; mi++)
#pragma unroll
            for (int ni = 0; ni < 4; ni++)
                acc[mi][ni] = __builtin_amdgcn_mfma_f32_16x16x32_bf16(
                    af[mi], bf[ni], acc[mi][ni], 0, 0, 0);
        if (k0 + 32 < GK) writeW(buf ^ 1);
    }

    float bvals[4];
#pragma unroll
    for (int ni = 0; ni < 4; ni++) bvals[ni] = bias[n0 + wc + ni * 16 + l16];
#pragma unroll
    for (int mi = 0; mi < 4; mi++)
#pragma unroll
        for (int reg = 0; reg < 4; reg++) {
            int m = m0 + wr + mi * 16 + quad * 4 + reg;
            if (m < M_) {
                float* row = out + (size_t)m * C_ + n0 + wc;
#pragma unroll
                for (int ni = 0; ni < 4; ni++)
                    row[ni * 16 + l16] = acc[mi][ni][reg] + bvals[ni];
            }
        }
}

// ---------------------------------------------------------------------------
// FUSED attention v8 (exact revert to the R3/R4 47.2 µs version):
// 32 query rows per wave (two l16-groups sharing every K/V ds_read), grid
// 256 = 64 bh x 4 mt, blockIdx%8 = h for XCD L2 co-location. Swapped-QK
// registers-only softmax; bias A prefetched one tile ahead, B in-tile.
// ---------------------------------------------------------------------------
#define RT_ 288   // rows per block (9 waves x 32)

__global__ __launch_bounds__(576, 3) void attn_fused(
        const unsigned short* __restrict__ qg,
        const unsigned short* __restrict__ kg,
        const unsigned short* __restrict__ vtc,
        const unsigned short* __restrict__ bigtab,
        unsigned short* __restrict__ ob) {
    __shared__ __align__(16) unsigned short Ks[2][6144];   // 24 KB
    __shared__ __align__(16) unsigned short Vs[2][7680];   // 30 KB

    int tid = threadIdx.x;
    int w = tid >> 6, lane = tid & 63;
    int quad = lane >> 4, l16 = lane & 15;

    int lin = blockIdx.x;            // 256 blocks
    int bh = lin & 63;               // blockIdx%8 = bh&7 = h -> XCD co-location
    int mt = lin >> 6;               // 0..3
    int b = bh >> 3, h = bh & 7;

    const unsigned short* qp = qg + (size_t)bh * N_ * HD_;
    const unsigned short* kp = kg + (size_t)bh * N_ * HD_;
    const unsigned short* vp = vtc + (size_t)bh * VST * VCS;

    int qrA = mt * RT_ + w * 32 + l16;           // qgrp A rows (A-layout, l16)
    const unsigned short* btA = bigtab + ((size_t)h * 1152 + qrA) * BW_ + quad * 4;
    const unsigned short* btB = btA + (size_t)16 * BW_;

    short8 qfA[2], qfB[2];
    {
        int rowA = min(qrA, N_ - 1);
        int rowB = min(qrA + 16, N_ - 1);
        qfA[0] = *(const short8*)(qp + (size_t)rowA * HD_ + quad * 8);
        qfA[1] = *(const short8*)(qp + (size_t)rowA * HD_ + 32 + quad * 8);
        qfB[0] = *(const short8*)(qp + (size_t)rowB * HD_ + quad * 8);
        qfB[1] = *(const short8*)(qp + (size_t)rowB * HD_ + 32 + quad * 8);
    }

    f32x4 oA[4], oB[4], lA, lB;
    const f32x4 zero4 = {0.f, 0.f, 0.f, 0.f};
#pragma unroll
    for (int g2 = 0; g2 < 4; g2++) { oA[g2] = zero4; oB[g2] = zero4; }
    lA = zero4; lB = zero4;
    short8 ones;
    {
        short one_bf = (short)0x3F80;
#pragma unroll
        for (int j = 0; j < 8; j++) ones[j] = one_bf;
    }

    // balanced staging: 27 64-chunk blocks (12 K + 15 V), 3 per wave.
    auto stage = [&](int t, int buf) {
#pragma unroll
        for (int r2 = 0; r2 < 3; r2++) {
            int cb = w * 3 + r2;                 // 0..26, uniform per wave
            if (cb < 12) {
                int ch = cb * 64 + lane;
                int ct = ch >> 7, rem = ch & 127;
                int oct = rem >> 4, k16 = rem & 15;
                int key = min(t * 96 + ct * 16 + k16, N_ - 1);
                load_lds16(kp + (size_t)key * HD_ + oct * 8, &Ks[buf][cb * 512]);
            } else {
                int vb = cb - 12;
                load_lds16(vp + (size_t)t * 3 * VCS + (size_t)(vb * 64 + lane) * 8,
                           &Vs[buf][vb * 512]);
            }
        }
    };

    us4 bAc[6], bAn[6];
#pragma unroll
    for (int i = 0; i < 6; i++)
        bAn[i] = *(const us4*)(btA + (i >> 1) * 32 + (i & 1) * 16);
    stage(0, 0);

#pragma unroll 1
    for (int t = 0; t < 11; t++) {
        int buf = t & 1;
        __syncthreads();                  // Ks/Vs[buf] ready (vmcnt drained)

#pragma unroll
        for (int i = 0; i < 6; i++) bAc[i] = bAn[i];
        us4 bB[6];
        {
            const unsigned short* btp = btB + t * 96;
#pragma unroll
            for (int i = 0; i < 6; i++)
                bB[i] = *(const us4*)(btp + (i >> 1) * 32 + (i & 1) * 16);
        }
        if (t < 10) {
            const unsigned short* btp = btA + (t + 1) * 96;
#pragma unroll
            for (int i = 0; i < 6; i++)
                bAn[i] = *(const us4*)(btp + (i >> 1) * 32 + (i & 1) * 16);
            stage(t + 1, buf ^ 1);
        }

#pragma unroll
        for (int ks = 0; ks < 3; ks++) {
            f32x4 sA[2], sB[2];
#pragma unroll
            for (int ctl = 0; ctl < 2; ctl++) {
                int ct = ks * 2 + ctl;
                short8 kf0 = *(const short8*)&Ks[buf][(ct * 128 + quad * 16 + l16) * 8];
                short8 kf1 = *(const short8*)&Ks[buf][(ct * 128 + (4 + quad) * 16 + l16) * 8];
                sA[ctl] = __builtin_amdgcn_mfma_f32_16x16x32_bf16(kf0, qfA[0], zero4, 0, 0, 0);
                sA[ctl] = __builtin_amdgcn_mfma_f32_16x16x32_bf16(kf1, qfA[1], sA[ctl], 0, 0, 0);
                sB[ctl] = __builtin_amdgcn_mfma_f32_16x16x32_bf16(kf0, qfB[0], zero4, 0, 0, 0);
                sB[ctl] = __builtin_amdgcn_mfma_f32_16x16x32_bf16(kf1, qfB[1], sB[ctl], 0, 0, 0);
            }
            const unsigned short* vcp = &Vs[buf][ks * 2560 + quad * 8];
            short8 vf[4];
#pragma unroll
            for (int g2 = 0; g2 < 4; g2++)
                vf[g2] = *(const short8*)(vcp + (g2 * 16 + l16) * 40);

            short8 pfA;
#pragma unroll
            for (int e = 0; e < 8; e++) {
                int par = e >> 2, r = e & 3;
                float bia = h2f(bAc[ks * 2 + par][r]);
                pfA[e] = (short)bf16u(fexp2(sA[par][r] + bia));
            }
            __builtin_amdgcn_s_setprio(1);
#pragma unroll
            for (int g2 = 0; g2 < 4; g2++)
                oA[g2] = __builtin_amdgcn_mfma_f32_16x16x32_bf16(pfA, vf[g2], oA[g2], 0, 0, 0);
            lA = __builtin_amdgcn_mfma_f32_16x16x32_bf16(pfA, ones, lA, 0, 0, 0);
            __builtin_amdgcn_s_setprio(0);

            short8 pfB;
#pragma unroll
            for (int e = 0; e < 8; e++) {
                int par = e >> 2, r = e & 3;
                float bia = h2f(bB[ks * 2 + par][r]);
                pfB[e] = (short)bf16u(fexp2(sB[par][r] + bia));
            }
            __builtin_amdgcn_s_setprio(1);
#pragma unroll
            for (int g2 = 0; g2 < 4; g2++)
                oB[g2] = __builtin_amdgcn_mfma_f32_16x16x32_bf16(pfB, vf[g2], oB[g2], 0, 0, 0);
            lB = __builtin_amdgcn_mfma_f32_16x16x32_bf16(pfB, ones, lB, 0, 0, 0);
            __builtin_amdgcn_s_setprio(0);
        }
    }

#pragma unroll
    for (int grp = 0; grp < 2; grp++) {
        int rbase = mt * RT_ + w * 32 + grp * 16 + quad * 4;
        const f32x4* oX = grp ? oB : oA;
        const f32x4& lX = grp ? lB : lA;
#pragma unroll
        for (int reg = 0; reg < 4; reg++) {
            int r = rbase + reg;
            if (r < N_) {
                float inv = 1.0f / lX[reg];
                unsigned short* orow = ob + ((size_t)b * N_ + r) * C_ + h * HD_ + l16;
#pragma unroll
                for (int g2 = 0; g2 < 4; g2++)
                    orow[g2 * 16] = bf16u(oX[g2][reg] * inv);
            }
        }
    }
}

// ---------------------------------------------------------------------------
extern "C" void kernel_launch(void* const* d_in, const int* in_sizes, int n_in,
                              void* d_out, int out_size, void* d_ws, size_t ws_size,
                              hipStream_t stream) {
    const float* x      = (const float*)d_in[0];
    const float* qkv_w  = (const float*)d_in[1];
    const float* proj_w = (const float*)d_in[2];
    const float* proj_b = (const float*)d_in[3];
    const float* wg_w   = (const float*)d_in[4];
    const float* wg_b   = (const float*)d_in[5];
    float* out = (float*)d_out;

    const size_t per = PER_;
    char* ws = (char*)d_ws;
    unsigned short* bigtab = (unsigned short*)ws;                   // 19,464,192 B
    unsigned short* qb     = bigtab + (size_t)8 * 1152 * BW_;       //  8,396,800 B
    unsigned short* kb     = qb + per;                              //  8,396,800 B
    unsigned short* vtc    = kb + per;                              // 11,796,480 B
    unsigned short* ob     = vtc + (size_t)64 * VST * VCS;          //  8,396,800 B

    gemm_qkv_mfma<<<EXP_BLKS + 12 * 65, 256, 0, stream>>>(
        x, qkv_w, wg_w, wg_b, qb, kb, vtc, bigtab);
    attn_fused<<<256, 576, 0, stream>>>(qb, kb, vtc, bigtab, ob);
    gemm_proj_mfma<<<dim3(4, 65), 256, 0, stream>>>(ob, proj_w, proj_b, out);
}

// Round 7
// 183.557 us; speedup vs baseline: 1.0792x; 1.0024x over previous
//
#include <hip/hip_runtime.h>
#include <hip/hip_bf16.h>
#include <hip/hip_fp16.h>
#include <math.h>

#define B_  8
#define N_  1025
#define C_  512
#define H_  8
#define HD_ 64
#define M_  (B_ * N_)   // 8200
#define VCS 2560        // shorts per vtc chunk-block: 64 dims * 40 (32 keys + 8 pad)
#define VST 36          // vtc chunk-blocks per bh (33 used)
#define BW_ 1056        // bigtab cols (11 x 96-key tiles)
#define PER_ ((size_t)B_ * H_ * N_ * HD_)      // 4,198,400
#define EXP_BLKS 256
#define GK 512

typedef __attribute__((ext_vector_type(8))) short short8;
typedef __attribute__((ext_vector_type(4))) float f32x4;
typedef __attribute__((ext_vector_type(4))) unsigned short us4;

__device__ inline unsigned short bf16u(float x) {
    __hip_bfloat16 t = __float2bfloat16(x);
    return *(unsigned short*)&t;
}
__device__ inline float fexp2(float x) {   // 2^x via v_exp_f32
    float r;
    asm("v_exp_f32 %0, %1" : "=v"(r) : "v"(x));
    return r;
}
__device__ inline float h2f(unsigned short u) {
    __half_raw hr; hr.x = u;
    return __half2float(__half(hr));
}
__device__ inline void load_lds16(const void* g, void* l) {
    __builtin_amdgcn_global_load_lds(
        (const __attribute__((address_space(1))) unsigned int*)g,
        (__attribute__((address_space(3))) unsigned int*)l, 16, 0, 0);
}
__device__ inline short8 pack8(float4 u0, float4 u1) {
    short8 r;
    r[0] = (short)bf16u(u0.x); r[1] = (short)bf16u(u0.y);
    r[2] = (short)bf16u(u0.z); r[3] = (short)bf16u(u0.w);
    r[4] = (short)bf16u(u1.x); r[5] = (short)bf16u(u1.y);
    r[6] = (short)bf16u(u1.z); r[7] = (short)bf16u(u1.w);
    return r;
}

// ---------------------------------------------------------------------------
// GEMM QKV + bigtab, ONE dispatch.
//  blocks [0,256): bigtab expansion (unchanged).
//  blocks [256,1036): 128x128 MFMA gemm, BK=32, f32 reg-staged to bf16 LDS.
//  NEW (R7): (1) bijective XCD swizzle (780 = 8*97+4): per-XCD contiguous
//  wgid, bx fastest -> each A-tile fetched by ONE XCD, working set (B 3MB +
//  A-tile) L2-resident -> staged loads become L2 hits. (2) LDS granule XOR
//  swizzle g = quad ^ ((row>>1)&3): ds_read_b128 goes 8-way-conflict -> free
//  (2 lanes/bank); writes remain conflict-free (per-row permutation).
// ---------------------------------------------------------------------------
__global__ __launch_bounds__(256) void gemm_qkv_mfma(
        const float* __restrict__ x, const float* __restrict__ qkv_w,
        const float* __restrict__ wg_w, const float* __restrict__ wg_b,
        unsigned short* __restrict__ qb, unsigned short* __restrict__ kb,
        unsigned short* __restrict__ vtc, unsigned short* __restrict__ big) {
    __shared__ __align__(16) unsigned short As[2][4096];
    __shared__ __align__(16) unsigned short Bs[2][4096];
    int lin = blockIdx.x;
    int tid = threadIdx.x;

    if (lin < EXP_BLKS) {
        float* tl = (float*)&As[0][0];          // 4 KB of the 16 KB As
        float* sT = (float*)&Bs[0][0];
        float* cT = sT + 256;
        int h = lin >> 5, rs = lin & 31;
        const float* w = wg_w + h * 64;
        {
            const float fr[8] = {1.0f, 0.421696503f, 0.177827941f, 0.074989421f,
                                 0.031622777f, 0.013335214f, 0.005623413f, 0.002371374f};
            int a = tid >> 3, k = tid & 7;
            float dxv = logf(fmaxf((float)a * (1.0f / 33.0f), 0.001f));
            float ang = 100.0f * dxv * fr[k];
            sT[tid] = sinf(ang);
            cT[tid] = cosf(ang);
        }
        __syncthreads();
        float wb = wg_b[h];
        float wtail = 0.f;
#pragma unroll
        for (int k = 0; k < 8; k++) wtail += w[48 + k] + w[56 + k];
#pragma unroll 1
        for (int e = tid; e < 1024; e += 256) {
            int a = e >> 5, b = e & 31;
            float acc = wb + wtail;
#pragma unroll
            for (int k = 0; k < 8; k++) {
                acc += w[k]      * sT[a * 8 + k];
                acc += w[8 + k]  * sT[b * 8 + k];
                acc += w[32 + k] * cT[a * 8 + k];
                acc += w[40 + k] * cT[b * 8 + k];
            }
            tl[e] = log2f(fmaxf(fmaxf(acc, 0.0f), 1e-6f));
        }
        __syncthreads();
        int rbase = rs * 36;
#pragma unroll 1
        for (int e8 = tid; e8 < 36 * 132; e8 += 256) {
            int rr = e8 / 132;
            int cg = e8 - rr * 132;
            int r = rbase + rr;
            int c0 = cg * 8;
            int i = min(r, 1024) - 1;
            int ix = i >> 5, iy = i & 31;
            unsigned short o8[8];
#pragma unroll
            for (int e = 0; e < 8; e++) {
                int c = c0 + e;
                float v;
                if (r == 0 || c == 0) v = 0.f;
                else if (c > 1024)    v = -60000.f;
                else {
                    int j = c - 1;
                    int da = __sad(ix, j >> 5, 0u);
                    int db = __sad(iy, j & 31, 0u);
                    v = tl[da * 32 + db];
                }
                __half hv = __float2half(v);
                o8[e] = *(unsigned short*)&hv;
            }
            *(short8*)(big + ((size_t)h * 1152 + r) * BW_ + c0) = *(short8*)o8;
        }
        return;
    }

    // bijective XCD swizzle: 780 blocks = 8*97+4 (m204). orig%8 = HW XCD.
    int orig = lin - EXP_BLKS;
    int xcd = orig & 7, pos = orig >> 3;
    int wgid = (xcd < 4) ? xcd * 98 + pos : 392 + (xcd - 4) * 97 + pos;
    int bx = wgid % 12, by = wgid / 12;        // bx fastest: A-tile reused 12x in-XCD

    int wv = tid >> 6, lane = tid & 63;
    int quad = lane >> 4, l16 = lane & 15;
    int m0 = by * 128, n0 = bx * 128;
    int wr = (wv >> 1) * 64, wc = (wv & 1) * 64;

    int ar0 = min(m0 + (tid >> 2), M_ - 1);
    int ar1 = min(m0 + 64 + (tid >> 2), M_ - 1);
    int br0 = n0 + (tid >> 2), br1 = n0 + 64 + (tid >> 2);
    int ac = (tid & 3) * 8;

    int which = n0 >> 9;                       // 0=q 1=k 2=v
    int h = ((n0 + wc) >> 6) & 7;

    f32x4 acc[4][4];
    const f32x4 zero4 = {0.f, 0.f, 0.f, 0.f};
#pragma unroll
    for (int mi = 0; mi < 4; mi++)
#pragma unroll
        for (int ni = 0; ni < 4; ni++) acc[mi][ni] = zero4;

    float4 ra0, ra1, ra2, ra3, rb0, rb1, rb2, rb3;
    auto loadAll = [&](int k0) {
        const float* pa0 = x + (size_t)ar0 * GK + k0 + ac;
        const float* pa1 = x + (size_t)ar1 * GK + k0 + ac;
        const float* pb0 = qkv_w + (size_t)br0 * GK + k0 + ac;
        const float* pb1 = qkv_w + (size_t)br1 * GK + k0 + ac;
        ra0 = *(const float4*)pa0; ra1 = *(const float4*)(pa0 + 4);
        ra2 = *(const float4*)pa1; ra3 = *(const float4*)(pa1 + 4);
        rb0 = *(const float4*)pb0; rb1 = *(const float4*)(pb0 + 4);
        rb2 = *(const float4*)pb1; rb3 = *(const float4*)(pb1 + 4);
    };
    int wrow = tid >> 2;                        // 0..63
    int wg = ((tid & 3) ^ (wrow >> 1)) & 3;     // granule swizzle (write side)
    auto writeAll = [&](int buf) {
        *(short8*)&As[buf][wrow * 32 + wg * 8]        = pack8(ra0, ra1);
        *(short8*)&As[buf][(wrow + 64) * 32 + wg * 8] = pack8(ra2, ra3);
        *(short8*)&Bs[buf][wrow * 32 + wg * 8]        = pack8(rb0, rb1);
        *(short8*)&Bs[buf][(wrow + 64) * 32 + wg * 8] = pack8(rb2, rb3);
    };
    loadAll(0);
    writeAll(0);

    for (int k0 = 0; k0 < GK; k0 += 32) {
        int buf = (k0 >> 5) & 1;
        if (k0 + 32 < GK) loadAll(k0 + 32);    // L2-hit latency hides under barrier+MFMA
        __syncthreads();                       // buf's ds_writes visible
        short8 af[4], bf[4];
#pragma unroll
        for (int mi = 0; mi < 4; mi++) {
            int rr = wr + mi * 16 + l16;
            af[mi] = *(const short8*)&As[buf][rr * 32 + ((quad ^ (rr >> 1)) & 3) * 8];
        }
#pragma unroll
        for (int ni = 0; ni < 4; ni++) {
            int rr = wc + ni * 16 + l16;
            bf[ni] = *(const short8*)&Bs[buf][rr * 32 + ((quad ^ (rr >> 1)) & 3) * 8];
        }
#pragma unroll
        for (int mi = 0; mi < 4; mi++)
#pragma unroll
            for (int ni = 0; ni < 4; ni++)
                acc[mi][ni] = __builtin_amdgcn_mfma_f32_16x16x32_bf16(
                    bf[ni], af[mi], acc[mi][ni], 0, 0, 0);
        if (k0 + 32 < GK) writeAll(buf ^ 1);   // cvt+ds_write after MFMA (T14)
    }

    if (which < 2) {
        unsigned short* dst = (which == 0) ? qb : kb;
        float sc = (which == 0) ? 0.18033688f : 1.0f;   // 0.125 * log2(e)
#pragma unroll
        for (int mi = 0; mi < 4; mi++) {
            int m = m0 + wr + mi * 16 + l16;
            if (m < M_) {
                int bb = m / N_;
                int i  = m - bb * N_;
                unsigned short* row = dst + ((size_t)(bb * H_ + h) * N_ + i) * HD_;
#pragma unroll
                for (int ni = 0; ni < 4; ni++) {
                    ushort4 pk;
                    pk.x = bf16u(acc[mi][ni][0] * sc);
                    pk.y = bf16u(acc[mi][ni][1] * sc);
                    pk.z = bf16u(acc[mi][ni][2] * sc);
                    pk.w = bf16u(acc[mi][ni][3] * sc);
                    *(ushort4*)(row + ni * 16 + quad * 4) = pk;
                }
            }
        }
    } else {
#pragma unroll
        for (int mi = 0; mi < 4; mi++) {
            int m = m0 + wr + mi * 16 + l16;
            if (m < M_) {
                int bb = m / N_;
                int i  = m - bb * N_;
                int ch = i >> 5, key = i & 31;
                int slot = ((key >> 2) & 3) * 8 + ((key >> 4) << 2) + (key & 3);
                unsigned short* base = vtc + ((size_t)(bb * H_ + h) * VST + ch) * VCS + slot;
#pragma unroll
                for (int ni = 0; ni < 4; ni++)
#pragma unroll
                    for (int reg = 0; reg < 4; reg++)
                        base[(ni * 16 + quad * 4 + reg) * 40] = bf16u(acc[mi][ni][reg]);
            }
        }
    }
}

// ---------------------------------------------------------------------------
// GEMM proj: A-side (ob, bf16) via global_load_lds with PRE-SWIZZLED global
// col (rule #21 both-sides: linear LDS dest + swizzled source + swizzled
// read); W-side (proj_w, f32) reg-staged. 1D grid 260 = 8*32+4, bijective
// XCD swizzle, bx fastest.
// ---------------------------------------------------------------------------
__global__ __launch_bounds__(256) void gemm_proj_mfma(
        const unsigned short* __restrict__ A, const float* __restrict__ Wf,
        const float* __restrict__ bias, float* __restrict__ out) {
    __shared__ __align__(16) unsigned short As[2][4096];
    __shared__ __align__(16) unsigned short Bs[2][4096];
    int tid = threadIdx.x;
    int w = tid >> 6, lane = tid & 63;
    int quad = lane >> 4, l16 = lane & 15;

    int orig = blockIdx.x;                     // 260 = 8*32+4
    int xcd = orig & 7, pos = orig >> 3;
    int wgid = (xcd < 4) ? xcd * 33 + pos : 132 + (xcd - 4) * 32 + pos;
    int bx = wgid & 3, by = wgid >> 2;

    int m0 = by * 128;
    int n0 = bx * 128;
    int wr = (w >> 1) * 64, wc = (w & 1) * 64;

    int ar0 = min(m0 + (tid >> 2), M_ - 1);
    int ar1 = min(m0 + 64 + (tid >> 2), M_ - 1);
    int br0 = n0 + (tid >> 2), br1 = n0 + 64 + (tid >> 2);
    int acW = (tid & 3) * 8;
    int acA = (((tid & 3) ^ ((tid >> 3) & 3))) * 8;   // pre-swizzled global col

    f32x4 acc[4][4];
    const f32x4 zero4 = {0.f, 0.f, 0.f, 0.f};
#pragma unroll
    for (int mi = 0; mi < 4; mi++)
#pragma unroll
        for (int ni = 0; ni < 4; ni++) acc[mi][ni] = zero4;

    auto stageA = [&](int k0, int buf) {
        load_lds16(A + (size_t)ar0 * GK + k0 + acA, &As[buf][w * 512]);
        load_lds16(A + (size_t)ar1 * GK + k0 + acA, &As[buf][2048 + w * 512]);
    };
    float4 rw0, rw1, rw2, rw3;
    auto loadW = [&](int k0) {
        const float* p0 = Wf + (size_t)br0 * GK + k0 + acW;
        const float* p1 = Wf + (size_t)br1 * GK + k0 + acW;
        rw0 = *(const float4*)p0; rw1 = *(const float4*)(p0 + 4);
        rw2 = *(const float4*)p1; rw3 = *(const float4*)(p1 + 4);
    };
    int wrow = tid >> 2;
    int wg = ((tid & 3) ^ (wrow >> 1)) & 3;
    auto writeW = [&](int buf) {
        *(short8*)&Bs[buf][wrow * 32 + wg * 8]        = pack8(rw0, rw1);
        *(short8*)&Bs[buf][(wrow + 64) * 32 + wg * 8] = pack8(rw2, rw3);
    };
    stageA(0, 0);
    loadW(0);
    writeW(0);

    for (int k0 = 0; k0 < GK; k0 += 32) {
        int buf = (k0 >> 5) & 1;
        __syncthreads();                 // drains A load_lds + W ds_writes
        if (k0 + 32 < GK) { stageA(k0 + 32, buf ^ 1); loadW(k0 + 32); }
        short8 af[4], bf[4];
#pragma unroll
        for (int mi = 0; mi < 4; mi++) {
            int rr = wr + mi * 16 + l16;
            af[mi] = *(const short8*)&As[buf][rr * 32 + ((quad ^ (rr >> 1)) & 3) * 8];
        }
#pragma unroll
        for (int ni = 0; ni < 4; ni++) {
            int rr = wc + ni * 16 + l16;
            bf[ni] = *(const short8*)&Bs[buf][rr * 32 + ((quad ^ (rr >> 1)) & 3) * 8];
        }
#pragma unroll
        for (int mi = 0; mi < 4; mi++)
#pragma unroll
            for (int ni = 0; ni < 4; ni++)
                acc[mi][ni] = __builtin_amdgcn_mfma_f32_16x16x32_bf16(
                    af[mi], bf[ni], acc[mi][ni], 0, 0, 0);
        if (k0 + 32 < GK) writeW(buf ^ 1);
    }

    float bvals[4];
#pragma unroll
    for (int ni = 0; ni < 4; ni++) bvals[ni] = bias[n0 + wc + ni * 16 + l16];
#pragma unroll
    for (int mi = 0; mi < 4; mi++)
#pragma unroll
        for (int reg = 0; reg < 4; reg++) {
            int m = m0 + wr + mi * 16 + quad * 4 + reg;
            if (m < M_) {
                float* row = out + (size_t)m * C_ + n0 + wc;
#pragma unroll
                for (int ni = 0; ni < 4; ni++)
                    row[ni * 16 + l16] = acc[mi][ni][reg] + bvals[ni];
            }
        }
}

// ---------------------------------------------------------------------------
// FUSED attention v8 (UNCHANGED — the 47.2 µs anchor):
// 32 query rows per wave (two l16-groups sharing every K/V ds_read), grid
// 256 = 64 bh x 4 mt, blockIdx%8 = h for XCD L2 co-location. Swapped-QK
// registers-only softmax; bias A prefetched one tile ahead, B in-tile.
// ---------------------------------------------------------------------------
#define RT_ 288   // rows per block (9 waves x 32)

__global__ __launch_bounds__(576, 3) void attn_fused(
        const unsigned short* __restrict__ qg,
        const unsigned short* __restrict__ kg,
        const unsigned short* __restrict__ vtc,
        const unsigned short* __restrict__ bigtab,
        unsigned short* __restrict__ ob) {
    __shared__ __align__(16) unsigned short Ks[2][6144];   // 24 KB
    __shared__ __align__(16) unsigned short Vs[2][7680];   // 30 KB

    int tid = threadIdx.x;
    int w = tid >> 6, lane = tid & 63;
    int quad = lane >> 4, l16 = lane & 15;

    int lin = blockIdx.x;            // 256 blocks
    int bh = lin & 63;               // blockIdx%8 = bh&7 = h -> XCD co-location
    int mt = lin >> 6;               // 0..3
    int b = bh >> 3, h = bh & 7;

    const unsigned short* qp = qg + (size_t)bh * N_ * HD_;
    const unsigned short* kp = kg + (size_t)bh * N_ * HD_;
    const unsigned short* vp = vtc + (size_t)bh * VST * VCS;

    int qrA = mt * RT_ + w * 32 + l16;           // qgrp A rows (A-layout, l16)
    const unsigned short* btA = bigtab + ((size_t)h * 1152 + qrA) * BW_ + quad * 4;
    const unsigned short* btB = btA + (size_t)16 * BW_;

    short8 qfA[2], qfB[2];
    {
        int rowA = min(qrA, N_ - 1);
        int rowB = min(qrA + 16, N_ - 1);
        qfA[0] = *(const short8*)(qp + (size_t)rowA * HD_ + quad * 8);
        qfA[1] = *(const short8*)(qp + (size_t)rowA * HD_ + 32 + quad * 8);
        qfB[0] = *(const short8*)(qp + (size_t)rowB * HD_ + quad * 8);
        qfB[1] = *(const short8*)(qp + (size_t)rowB * HD_ + 32 + quad * 8);
    }

    f32x4 oA[4], oB[4], lA, lB;
    const f32x4 zero4 = {0.f, 0.f, 0.f, 0.f};
#pragma unroll
    for (int g2 = 0; g2 < 4; g2++) { oA[g2] = zero4; oB[g2] = zero4; }
    lA = zero4; lB = zero4;
    short8 ones;
    {
        short one_bf = (short)0x3F80;
#pragma unroll
        for (int j = 0; j < 8; j++) ones[j] = one_bf;
    }

    // balanced staging: 27 64-chunk blocks (12 K + 15 V), 3 per wave.
    auto stage = [&](int t, int buf) {
#pragma unroll
        for (int r2 = 0; r2 < 3; r2++) {
            int cb = w * 3 + r2;                 // 0..26, uniform per wave
            if (cb < 12) {
                int ch = cb * 64 + lane;
                int ct = ch >> 7, rem = ch & 127;
                int oct = rem >> 4, k16 = rem & 15;
                int key = min(t * 96 + ct * 16 + k16, N_ - 1);
                load_lds16(kp + (size_t)key * HD_ + oct * 8, &Ks[buf][cb * 512]);
            } else {
                int vb = cb - 12;
                load_lds16(vp + (size_t)t * 3 * VCS + (size_t)(vb * 64 + lane) * 8,
                           &Vs[buf][vb * 512]);
            }
        }
    };

    us4 bAc[6], bAn[6];
#pragma unroll
    for (int i = 0; i < 6; i++)
        bAn[i] = *(const us4*)(btA + (i >> 1) * 32 + (i & 1) * 16);
    stage(0, 0);

#pragma unroll 1
    for (int t = 0; t < 11; t++) {
        int buf = t & 1;
        __syncthreads();                  // Ks/Vs[buf] ready (vmcnt drained)

#pragma unroll
        for (int i = 0; i < 6; i++) bAc[i] = bAn[i];
        us4 bB[6];
        {
            const unsigned short* btp = btB + t * 96;
#pragma unroll
            for (int i = 0; i < 6; i++)
                bB[i] = *(const us4*)(btp + (i >> 1) * 32 + (i & 1) * 16);
        }
        if (t < 10) {
            const unsigned short* btp = btA + (t + 1) * 96;
#pragma unroll
            for (int i = 0; i < 6; i++)
                bAn[i] = *(const us4*)(btp + (i >> 1) * 32 + (i & 1) * 16);
            stage(t + 1, buf ^ 1);
        }

#pragma unroll
        for (int ks = 0; ks < 3; ks++) {
            f32x4 sA[2], sB[2];
#pragma unroll
            for (int ctl = 0; ctl < 2; ctl++) {
                int ct = ks * 2 + ctl;
                short8 kf0 = *(const short8*)&Ks[buf][(ct * 128 + quad * 16 + l16) * 8];
                short8 kf1 = *(const short8*)&Ks[buf][(ct * 128 + (4 + quad) * 16 + l16) * 8];
                sA[ctl] = __builtin_amdgcn_mfma_f32_16x16x32_bf16(kf0, qfA[0], zero4, 0, 0, 0);
                sA[ctl] = __builtin_amdgcn_mfma_f32_16x16x32_bf16(kf1, qfA[1], sA[ctl], 0, 0, 0);
                sB[ctl] = __builtin_amdgcn_mfma_f32_16x16x32_bf16(kf0, qfB[0], zero4, 0, 0, 0);
                sB[ctl] = __builtin_amdgcn_mfma_f32_16x16x32_bf16(kf1, qfB[1], sB[ctl], 0, 0, 0);
            }
            const unsigned short* vcp = &Vs[buf][ks * 2560 + quad * 8];
            short8 vf[4];
#pragma unroll
            for (int g2 = 0; g2 < 4; g2++)
                vf[g2] = *(const short8*)(vcp + (g2 * 16 + l16) * 40);

            short8 pfA;
#pragma unroll
            for (int e = 0; e < 8; e++) {
                int par = e >> 2, r = e & 3;
                float bia = h2f(bAc[ks * 2 + par][r]);
                pfA[e] = (short)bf16u(fexp2(sA[par][r] + bia));
            }
            __builtin_amdgcn_s_setprio(1);
#pragma unroll
            for (int g2 = 0; g2 < 4; g2++)
                oA[g2] = __builtin_amdgcn_mfma_f32_16x16x32_bf16(pfA, vf[g2], oA[g2], 0, 0, 0);
            lA = __builtin_amdgcn_mfma_f32_16x16x32_bf16(pfA, ones, lA, 0, 0, 0);
            __builtin_amdgcn_s_setprio(0);

            short8 pfB;
#pragma unroll
            for (int e = 0; e < 8; e++) {
                int par = e >> 2, r = e & 3;
                float bia = h2f(bB[ks * 2 + par][r]);
                pfB[e] = (short)bf16u(fexp2(sB[par][r] + bia));
            }
            __builtin_amdgcn_s_setprio(1);
#pragma unroll
            for (int g2 = 0; g2 < 4; g2++)
                oB[g2] = __builtin_amdgcn_mfma_f32_16x16x32_bf16(pfB, vf[g2], oB[g2], 0, 0, 0);
            lB = __builtin_amdgcn_mfma_f32_16x16x32_bf16(pfB, ones, lB, 0, 0, 0);
            __builtin_amdgcn_s_setprio(0);
        }
    }

#pragma unroll
    for (int grp = 0; grp < 2; grp++) {
        int rbase = mt * RT_ + w * 32 + grp * 16 + quad * 4;
        const f32x4* oX = grp ? oB : oA;
        const f32x4& lX = grp ? lB : lA;
#pragma unroll
        for (int reg = 0; reg < 4; reg++) {
            int r = rbase + reg;
            if (r < N_) {
                float inv = 1.0f / lX[reg];
                unsigned short* orow = ob + ((size_t)b * N_ + r) * C_ + h * HD_ + l16;
#pragma unroll
                for (int g2 = 0; g2 < 4; g2++)
                    orow[g2 * 16] = bf16u(oX[g2][reg] * inv);
            }
        }
    }
}

// ---------------------------------------------------------------------------
extern "C" void kernel_launch(void* const* d_in, const int* in_sizes, int n_in,
                              void* d_out, int out_size, void* d_ws, size_t ws_size,
                              hipStream_t stream) {
    const float* x      = (const float*)d_in[0];
    const float* qkv_w  = (const float*)d_in[1];
    const float* proj_w = (const float*)d_in[2];
    const float* proj_b = (const float*)d_in[3];
    const float* wg_w   = (const float*)d_in[4];
    const float* wg_b   = (const float*)d_in[5];
    float* out = (float*)d_out;

    const size_t per = PER_;
    char* ws = (char*)d_ws;
    unsigned short* bigtab = (unsigned short*)ws;                   // 19,464,192 B
    unsigned short* qb     = bigtab + (size_t)8 * 1152 * BW_;       //  8,396,800 B
    unsigned short* kb     = qb + per;                              //  8,396,800 B
    unsigned short* vtc    = kb + per;                              // 11,796,480 B
    unsigned short* ob     = vtc + (size_t)64 * VST * VCS;          //  8,396,800 B

    gemm_qkv_mfma<<<EXP_BLKS + 12 * 65, 256, 0, stream>>>(
        x, qkv_w, wg_w, wg_b, qb, kb, vtc, bigtab);
    attn_fused<<<256, 576, 0, stream>>>(qb, kb, vtc, bigtab, ob);
    gemm_proj_mfma<<<260, 256, 0, stream>>>(ob, proj_w, proj_b, out);
}

// Round 8
// 178.980 us; speedup vs baseline: 1.1068x; 1.0256x over previous
//
#include <hip/hip_runtime.h>
#include <hip/hip_bf16.h>
#include <hip/hip_fp16.h>
#include <math.h>

#define B_  8
#define N_  1025
#define C_  512
#define H_  8
#define HD_ 64
#define M_  (B_ * N_)   // 8200
#define VCS 2560        // shorts per vtc chunk-block: 64 dims * 40 (32 keys + 8 pad)
#define VST 36          // vtc chunk-blocks per bh (33 used)
#define BW_ 1056        // bigtab cols (11 x 96-key tiles)
#define PER_ ((size_t)B_ * H_ * N_ * HD_)      // 4,198,400
#define EXP_BLKS 256
#define GK 512

typedef __attribute__((ext_vector_type(8))) short short8;
typedef __attribute__((ext_vector_type(4))) float f32x4;
typedef __attribute__((ext_vector_type(4))) unsigned short us4;

__device__ inline unsigned short bf16u(float x) {
    __hip_bfloat16 t = __float2bfloat16(x);
    return *(unsigned short*)&t;
}
__device__ inline float fexp2(float x) {   // 2^x via v_exp_f32
    float r;
    asm("v_exp_f32 %0, %1" : "=v"(r) : "v"(x));
    return r;
}
__device__ inline float h2f(unsigned short u) {
    __half_raw hr; hr.x = u;
    return __half2float(__half(hr));
}
__device__ inline void load_lds16(const void* g, void* l) {
    __builtin_amdgcn_global_load_lds(
        (const __attribute__((address_space(1))) unsigned int*)g,
        (__attribute__((address_space(3))) unsigned int*)l, 16, 0, 0);
}
__device__ inline short8 pack8(float4 u0, float4 u1) {
    short8 r;
    r[0] = (short)bf16u(u0.x); r[1] = (short)bf16u(u0.y);
    r[2] = (short)bf16u(u0.z); r[3] = (short)bf16u(u0.w);
    r[4] = (short)bf16u(u1.x); r[5] = (short)bf16u(u1.y);
    r[6] = (short)bf16u(u1.z); r[7] = (short)bf16u(u1.w);
    return r;
}

struct TileRegs { float4 a0, a1, a2, a3, b0, b1, b2, b3; };

// ---------------------------------------------------------------------------
// GEMM QKV + bigtab, ONE dispatch.
//  blocks [0,256): bigtab expansion (unchanged).
//  blocks [256,1036): 128x128 MFMA gemm, BK=32.
//  R8: R7's null (FETCH/conflicts halved, time flat) => the limiter is the
//  compiler's vmcnt(0) drain at every barrier, which fully serialized the
//  loads issued immediately before it. New schedule (unroll x2, two NAMED
//  reg tile-sets tA/tB, distance-2):
//    barrier; issue load(tile k+2); compute buf[k&1]; ds_write(tile k+1 regs)
//  -> at any barrier the newest outstanding load is a full step old; the
//  ds_write's vmcnt wait is covered by ds_read+MFMA. XCD swizzle + LDS
//  granule swizzle kept from R7.
// ---------------------------------------------------------------------------
__global__ __launch_bounds__(256) void gemm_qkv_mfma(
        const float* __restrict__ x, const float* __restrict__ qkv_w,
        const float* __restrict__ wg_w, const float* __restrict__ wg_b,
        unsigned short* __restrict__ qb, unsigned short* __restrict__ kb,
        unsigned short* __restrict__ vtc, unsigned short* __restrict__ big) {
    __shared__ __align__(16) unsigned short As[2][4096];
    __shared__ __align__(16) unsigned short Bs[2][4096];
    int lin = blockIdx.x;
    int tid = threadIdx.x;

    if (lin < EXP_BLKS) {
        float* tl = (float*)&As[0][0];          // 4 KB of the 16 KB As
        float* sT = (float*)&Bs[0][0];
        float* cT = sT + 256;
        int h = lin >> 5, rs = lin & 31;
        const float* w = wg_w + h * 64;
        {
            const float fr[8] = {1.0f, 0.421696503f, 0.177827941f, 0.074989421f,
                                 0.031622777f, 0.013335214f, 0.005623413f, 0.002371374f};
            int a = tid >> 3, k = tid & 7;
            float dxv = logf(fmaxf((float)a * (1.0f / 33.0f), 0.001f));
            float ang = 100.0f * dxv * fr[k];
            sT[tid] = sinf(ang);
            cT[tid] = cosf(ang);
        }
        __syncthreads();
        float wb = wg_b[h];
        float wtail = 0.f;
#pragma unroll
        for (int k = 0; k < 8; k++) wtail += w[48 + k] + w[56 + k];
#pragma unroll 1
        for (int e = tid; e < 1024; e += 256) {
            int a = e >> 5, b = e & 31;
            float acc = wb + wtail;
#pragma unroll
            for (int k = 0; k < 8; k++) {
                acc += w[k]      * sT[a * 8 + k];
                acc += w[8 + k]  * sT[b * 8 + k];
                acc += w[32 + k] * cT[a * 8 + k];
                acc += w[40 + k] * cT[b * 8 + k];
            }
            tl[e] = log2f(fmaxf(fmaxf(acc, 0.0f), 1e-6f));
        }
        __syncthreads();
        int rbase = rs * 36;
#pragma unroll 1
        for (int e8 = tid; e8 < 36 * 132; e8 += 256) {
            int rr = e8 / 132;
            int cg = e8 - rr * 132;
            int r = rbase + rr;
            int c0 = cg * 8;
            int i = min(r, 1024) - 1;
            int ix = i >> 5, iy = i & 31;
            unsigned short o8[8];
#pragma unroll
            for (int e = 0; e < 8; e++) {
                int c = c0 + e;
                float v;
                if (r == 0 || c == 0) v = 0.f;
                else if (c > 1024)    v = -60000.f;
                else {
                    int j = c - 1;
                    int da = __sad(ix, j >> 5, 0u);
                    int db = __sad(iy, j & 31, 0u);
                    v = tl[da * 32 + db];
                }
                __half hv = __float2half(v);
                o8[e] = *(unsigned short*)&hv;
            }
            *(short8*)(big + ((size_t)h * 1152 + r) * BW_ + c0) = *(short8*)o8;
        }
        return;
    }

    // bijective XCD swizzle: 780 blocks = 8*97+4 (m204). orig%8 = HW XCD.
    int orig = lin - EXP_BLKS;
    int xcd = orig & 7, pos = orig >> 3;
    int wgid = (xcd < 4) ? xcd * 98 + pos : 392 + (xcd - 4) * 97 + pos;
    int bx = wgid % 12, by = wgid / 12;        // bx fastest: A-tile reused 12x in-XCD

    int wv = tid >> 6, lane = tid & 63;
    int quad = lane >> 4, l16 = lane & 15;
    int m0 = by * 128, n0 = bx * 128;
    int wr = (wv >> 1) * 64, wc = (wv & 1) * 64;

    int ar0 = min(m0 + (tid >> 2), M_ - 1);
    int ar1 = min(m0 + 64 + (tid >> 2), M_ - 1);
    int br0 = n0 + (tid >> 2), br1 = n0 + 64 + (tid >> 2);
    int ac = (tid & 3) * 8;

    int which = n0 >> 9;                       // 0=q 1=k 2=v
    int h = ((n0 + wc) >> 6) & 7;

    f32x4 acc[4][4];
    const f32x4 zero4 = {0.f, 0.f, 0.f, 0.f};
#pragma unroll
    for (int mi = 0; mi < 4; mi++)
#pragma unroll
        for (int ni = 0; ni < 4; ni++) acc[mi][ni] = zero4;

    auto loadT = [&](int t, TileRegs& r) {
        int k0 = t * 32;
        const float* pa0 = x + (size_t)ar0 * GK + k0 + ac;
        const float* pa1 = x + (size_t)ar1 * GK + k0 + ac;
        const float* pb0 = qkv_w + (size_t)br0 * GK + k0 + ac;
        const float* pb1 = qkv_w + (size_t)br1 * GK + k0 + ac;
        r.a0 = *(const float4*)pa0; r.a1 = *(const float4*)(pa0 + 4);
        r.a2 = *(const float4*)pa1; r.a3 = *(const float4*)(pa1 + 4);
        r.b0 = *(const float4*)pb0; r.b1 = *(const float4*)(pb0 + 4);
        r.b2 = *(const float4*)pb1; r.b3 = *(const float4*)(pb1 + 4);
    };
    int wrow = tid >> 2;                        // 0..63
    int wg = ((tid & 3) ^ (wrow >> 1)) & 3;     // granule swizzle (write side)
    auto writeT = [&](const TileRegs& r, int buf) {
        *(short8*)&As[buf][wrow * 32 + wg * 8]        = pack8(r.a0, r.a1);
        *(short8*)&As[buf][(wrow + 64) * 32 + wg * 8] = pack8(r.a2, r.a3);
        *(short8*)&Bs[buf][wrow * 32 + wg * 8]        = pack8(r.b0, r.b1);
        *(short8*)&Bs[buf][(wrow + 64) * 32 + wg * 8] = pack8(r.b2, r.b3);
    };
    auto compute = [&](int buf) {
        short8 af[4], bf[4];
#pragma unroll
        for (int mi = 0; mi < 4; mi++) {
            int rr = wr + mi * 16 + l16;
            af[mi] = *(const short8*)&As[buf][rr * 32 + ((quad ^ (rr >> 1)) & 3) * 8];
        }
#pragma unroll
        for (int ni = 0; ni < 4; ni++) {
            int rr = wc + ni * 16 + l16;
            bf[ni] = *(const short8*)&Bs[buf][rr * 32 + ((quad ^ (rr >> 1)) & 3) * 8];
        }
#pragma unroll
        for (int mi = 0; mi < 4; mi++)
#pragma unroll
            for (int ni = 0; ni < 4; ni++)
                acc[mi][ni] = __builtin_amdgcn_mfma_f32_16x16x32_bf16(
                    bf[ni], af[mi], acc[mi][ni], 0, 0, 0);
    };

    TileRegs tA, tB;
    loadT(0, tA);
    writeT(tA, 0);          // vmcnt wait on tA here (prologue only)
    loadT(1, tB);

#pragma unroll 1
    for (int kk = 0; kk < 16; kk += 2) {
        __syncthreads();                 // newest outstanding load is 1 step old
        if (kk + 2 < 16) loadT(kk + 2, tA);
        compute(0);
        if (kk + 1 < 16) writeT(tB, 1);  // tB in flight a full step: covered
        __syncthreads();
        if (kk + 3 < 16) loadT(kk + 3, tB);
        compute(1);
        if (kk + 2 < 16) writeT(tA, 0);
    }

    if (which < 2) {
        unsigned short* dst = (which == 0) ? qb : kb;
        float sc = (which == 0) ? 0.18033688f : 1.0f;   // 0.125 * log2(e)
#pragma unroll
        for (int mi = 0; mi < 4; mi++) {
            int m = m0 + wr + mi * 16 + l16;
            if (m < M_) {
                int bb = m / N_;
                int i  = m - bb * N_;
                unsigned short* row = dst + ((size_t)(bb * H_ + h) * N_ + i) * HD_;
#pragma unroll
                for (int ni = 0; ni < 4; ni++) {
                    ushort4 pk;
                    pk.x = bf16u(acc[mi][ni][0] * sc);
                    pk.y = bf16u(acc[mi][ni][1] * sc);
                    pk.z = bf16u(acc[mi][ni][2] * sc);
                    pk.w = bf16u(acc[mi][ni][3] * sc);
                    *(ushort4*)(row + ni * 16 + quad * 4) = pk;
                }
            }
        }
    } else {
#pragma unroll
        for (int mi = 0; mi < 4; mi++) {
            int m = m0 + wr + mi * 16 + l16;
            if (m < M_) {
                int bb = m / N_;
                int i  = m - bb * N_;
                int ch = i >> 5, key = i & 31;
                int slot = ((key >> 2) & 3) * 8 + ((key >> 4) << 2) + (key & 3);
                unsigned short* base = vtc + ((size_t)(bb * H_ + h) * VST + ch) * VCS + slot;
#pragma unroll
                for (int ni = 0; ni < 4; ni++)
#pragma unroll
                    for (int reg = 0; reg < 4; reg++)
                        base[(ni * 16 + quad * 4 + reg) * 40] = bf16u(acc[mi][ni][reg]);
            }
        }
    }
}

// ---------------------------------------------------------------------------
// GEMM proj: A-side (ob, bf16) via global_load_lds (pre-swizzled global col,
// rule #21); W-side (proj_w, f32) reg-staged, NOW distance-2 (same schedule
// as gemm_qkv). 1D grid 260 = 8*32+4, bijective XCD swizzle, bx fastest.
// ---------------------------------------------------------------------------
struct WRegs { float4 w0, w1, w2, w3; };

__global__ __launch_bounds__(256) void gemm_proj_mfma(
        const unsigned short* __restrict__ A, const float* __restrict__ Wf,
        const float* __restrict__ bias, float* __restrict__ out) {
    __shared__ __align__(16) unsigned short As[2][4096];
    __shared__ __align__(16) unsigned short Bs[2][4096];
    int tid = threadIdx.x;
    int w = tid >> 6, lane = tid & 63;
    int quad = lane >> 4, l16 = lane & 15;

    int orig = blockIdx.x;                     // 260 = 8*32+4
    int xcd = orig & 7, pos = orig >> 3;
    int wgid = (xcd < 4) ? xcd * 33 + pos : 132 + (xcd - 4) * 32 + pos;
    int bx = wgid & 3, by = wgid >> 2;

    int m0 = by * 128;
    int n0 = bx * 128;
    int wr = (w >> 1) * 64, wc = (w & 1) * 64;

    int ar0 = min(m0 + (tid >> 2), M_ - 1);
    int ar1 = min(m0 + 64 + (tid >> 2), M_ - 1);
    int br0 = n0 + (tid >> 2), br1 = n0 + 64 + (tid >> 2);
    int acW = (tid & 3) * 8;
    int acA = (((tid & 3) ^ ((tid >> 3) & 3))) * 8;   // pre-swizzled global col

    f32x4 acc[4][4];
    const f32x4 zero4 = {0.f, 0.f, 0.f, 0.f};
#pragma unroll
    for (int mi = 0; mi < 4; mi++)
#pragma unroll
        for (int ni = 0; ni < 4; ni++) acc[mi][ni] = zero4;

    auto stageA = [&](int t, int buf) {
        int k0 = t * 32;
        load_lds16(A + (size_t)ar0 * GK + k0 + acA, &As[buf][w * 512]);
        load_lds16(A + (size_t)ar1 * GK + k0 + acA, &As[buf][2048 + w * 512]);
    };
    auto loadW = [&](int t, WRegs& r) {
        int k0 = t * 32;
        const float* p0 = Wf + (size_t)br0 * GK + k0 + acW;
        const float* p1 = Wf + (size_t)br1 * GK + k0 + acW;
        r.w0 = *(const float4*)p0; r.w1 = *(const float4*)(p0 + 4);
        r.w2 = *(const float4*)p1; r.w3 = *(const float4*)(p1 + 4);
    };
    int wrow = tid >> 2;
    int wg = ((tid & 3) ^ (wrow >> 1)) & 3;
    auto writeW = [&](const WRegs& r, int buf) {
        *(short8*)&Bs[buf][wrow * 32 + wg * 8]        = pack8(r.w0, r.w1);
        *(short8*)&Bs[buf][(wrow + 64) * 32 + wg * 8] = pack8(r.w2, r.w3);
    };
    auto compute = [&](int buf) {
        short8 af[4], bf[4];
#pragma unroll
        for (int mi = 0; mi < 4; mi++) {
            int rr = wr + mi * 16 + l16;
            af[mi] = *(const short8*)&As[buf][rr * 32 + ((quad ^ (rr >> 1)) & 3) * 8];
        }
#pragma unroll
        for (int ni = 0; ni < 4; ni++) {
            int rr = wc + ni * 16 + l16;
            bf[ni] = *(const short8*)&Bs[buf][rr * 32 + ((quad ^ (rr >> 1)) & 3) * 8];
        }
#pragma unroll
        for (int mi = 0; mi < 4; mi++)
#pragma unroll
            for (int ni = 0; ni < 4; ni++)
                acc[mi][ni] = __builtin_amdgcn_mfma_f32_16x16x32_bf16(
                    af[mi], bf[ni], acc[mi][ni], 0, 0, 0);
    };

    WRegs tA, tB;
    stageA(0, 0);
    loadW(0, tA);
    writeW(tA, 0);
    loadW(1, tB);

#pragma unroll 1
    for (int kk = 0; kk < 16; kk += 2) {
        __syncthreads();
        if (kk + 1 < 16) stageA(kk + 1, 1);
        if (kk + 2 < 16) loadW(kk + 2, tA);
        compute(0);
        if (kk + 1 < 16) writeW(tB, 1);
        __syncthreads();
        if (kk + 2 < 16) stageA(kk + 2, 0);
        if (kk + 3 < 16) loadW(kk + 3, tB);
        compute(1);
        if (kk + 2 < 16) writeW(tA, 0);
    }

    float bvals[4];
#pragma unroll
    for (int ni = 0; ni < 4; ni++) bvals[ni] = bias[n0 + wc + ni * 16 + l16];
#pragma unroll
    for (int mi = 0; mi < 4; mi++)
#pragma unroll
        for (int reg = 0; reg < 4; reg++) {
            int m = m0 + wr + mi * 16 + quad * 4 + reg;
            if (m < M_) {
                float* row = out + (size_t)m * C_ + n0 + wc;
#pragma unroll
                for (int ni = 0; ni < 4; ni++)
                    row[ni * 16 + l16] = acc[mi][ni][reg] + bvals[ni];
            }
        }
}

// ---------------------------------------------------------------------------
// FUSED attention v8 (UNCHANGED — the 47.2 µs anchor):
// 32 query rows per wave (two l16-groups sharing every K/V ds_read), grid
// 256 = 64 bh x 4 mt, blockIdx%8 = h for XCD L2 co-location. Swapped-QK
// registers-only softmax; bias A prefetched one tile ahead, B in-tile.
// ---------------------------------------------------------------------------
#define RT_ 288   // rows per block (9 waves x 32)

__global__ __launch_bounds__(576, 3) void attn_fused(
        const unsigned short* __restrict__ qg,
        const unsigned short* __restrict__ kg,
        const unsigned short* __restrict__ vtc,
        const unsigned short* __restrict__ bigtab,
        unsigned short* __restrict__ ob) {
    __shared__ __align__(16) unsigned short Ks[2][6144];   // 24 KB
    __shared__ __align__(16) unsigned short Vs[2][7680];   // 30 KB

    int tid = threadIdx.x;
    int w = tid >> 6, lane = tid & 63;
    int quad = lane >> 4, l16 = lane & 15;

    int lin = blockIdx.x;            // 256 blocks
    int bh = lin & 63;               // blockIdx%8 = bh&7 = h -> XCD co-location
    int mt = lin >> 6;               // 0..3
    int b = bh >> 3, h = bh & 7;

    const unsigned short* qp = qg + (size_t)bh * N_ * HD_;
    const unsigned short* kp = kg + (size_t)bh * N_ * HD_;
    const unsigned short* vp = vtc + (size_t)bh * VST * VCS;

    int qrA = mt * RT_ + w * 32 + l16;           // qgrp A rows (A-layout, l16)
    const unsigned short* btA = bigtab + ((size_t)h * 1152 + qrA) * BW_ + quad * 4;
    const unsigned short* btB = btA + (size_t)16 * BW_;

    short8 qfA[2], qfB[2];
    {
        int rowA = min(qrA, N_ - 1);
        int rowB = min(qrA + 16, N_ - 1);
        qfA[0] = *(const short8*)(qp + (size_t)rowA * HD_ + quad * 8);
        qfA[1] = *(const short8*)(qp + (size_t)rowA * HD_ + 32 + quad * 8);
        qfB[0] = *(const short8*)(qp + (size_t)rowB * HD_ + quad * 8);
        qfB[1] = *(const short8*)(qp + (size_t)rowB * HD_ + 32 + quad * 8);
    }

    f32x4 oA[4], oB[4], lA, lB;
    const f32x4 zero4 = {0.f, 0.f, 0.f, 0.f};
#pragma unroll
    for (int g2 = 0; g2 < 4; g2++) { oA[g2] = zero4; oB[g2] = zero4; }
    lA = zero4; lB = zero4;
    short8 ones;
    {
        short one_bf = (short)0x3F80;
#pragma unroll
        for (int j = 0; j < 8; j++) ones[j] = one_bf;
    }

    // balanced staging: 27 64-chunk blocks (12 K + 15 V), 3 per wave.
    auto stage = [&](int t, int buf) {
#pragma unroll
        for (int r2 = 0; r2 < 3; r2++) {
            int cb = w * 3 + r2;                 // 0..26, uniform per wave
            if (cb < 12) {
                int ch = cb * 64 + lane;
                int ct = ch >> 7, rem = ch & 127;
                int oct = rem >> 4, k16 = rem & 15;
                int key = min(t * 96 + ct * 16 + k16, N_ - 1);
                load_lds16(kp + (size_t)key * HD_ + oct * 8, &Ks[buf][cb * 512]);
            } else {
                int vb = cb - 12;
                load_lds16(vp + (size_t)t * 3 * VCS + (size_t)(vb * 64 + lane) * 8,
                           &Vs[buf][vb * 512]);
            }
        }
    };

    us4 bAc[6], bAn[6];
#pragma unroll
    for (int i = 0; i < 6; i++)
        bAn[i] = *(const us4*)(btA + (i >> 1) * 32 + (i & 1) * 16);
    stage(0, 0);

#pragma unroll 1
    for (int t = 0; t < 11; t++) {
        int buf = t & 1;
        __syncthreads();                  // Ks/Vs[buf] ready (vmcnt drained)

#pragma unroll
        for (int i = 0; i < 6; i++) bAc[i] = bAn[i];
        us4 bB[6];
        {
            const unsigned short* btp = btB + t * 96;
#pragma unroll
            for (int i = 0; i < 6; i++)
                bB[i] = *(const us4*)(btp + (i >> 1) * 32 + (i & 1) * 16);
        }
        if (t < 10) {
            const unsigned short* btp = btA + (t + 1) * 96;
#pragma unroll
            for (int i = 0; i < 6; i++)
                bAn[i] = *(const us4*)(btp + (i >> 1) * 32 + (i & 1) * 16);
            stage(t + 1, buf ^ 1);
        }

#pragma unroll
        for (int ks = 0; ks < 3; ks++) {
            f32x4 sA[2], sB[2];
#pragma unroll
            for (int ctl = 0; ctl < 2; ctl++) {
                int ct = ks * 2 + ctl;
                short8 kf0 = *(const short8*)&Ks[buf][(ct * 128 + quad * 16 + l16) * 8];
                short8 kf1 = *(const short8*)&Ks[buf][(ct * 128 + (4 + quad) * 16 + l16) * 8];
                sA[ctl] = __builtin_amdgcn_mfma_f32_16x16x32_bf16(kf0, qfA[0], zero4, 0, 0, 0);
                sA[ctl] = __builtin_amdgcn_mfma_f32_16x16x32_bf16(kf1, qfA[1], sA[ctl], 0, 0, 0);
                sB[ctl] = __builtin_amdgcn_mfma_f32_16x16x32_bf16(kf0, qfB[0], zero4, 0, 0, 0);
                sB[ctl] = __builtin_amdgcn_mfma_f32_16x16x32_bf16(kf1, qfB[1], sB[ctl], 0, 0, 0);
            }
            const unsigned short* vcp = &Vs[buf][ks * 2560 + quad * 8];
            short8 vf[4];
#pragma unroll
            for (int g2 = 0; g2 < 4; g2++)
                vf[g2] = *(const short8*)(vcp + (g2 * 16 + l16) * 40);

            short8 pfA;
#pragma unroll
            for (int e = 0; e < 8; e++) {
                int par = e >> 2, r = e & 3;
                float bia = h2f(bAc[ks * 2 + par][r]);
                pfA[e] = (short)bf16u(fexp2(sA[par][r] + bia));
            }
            __builtin_amdgcn_s_setprio(1);
#pragma unroll
            for (int g2 = 0; g2 < 4; g2++)
                oA[g2] = __builtin_amdgcn_mfma_f32_16x16x32_bf16(pfA, vf[g2], oA[g2], 0, 0, 0);
            lA = __builtin_amdgcn_mfma_f32_16x16x32_bf16(pfA, ones, lA, 0, 0, 0);
            __builtin_amdgcn_s_setprio(0);

            short8 pfB;
#pragma unroll
            for (int e = 0; e < 8; e++) {
                int par = e >> 2, r = e & 3;
                float bia = h2f(bB[ks * 2 + par][r]);
                pfB[e] = (short)bf16u(fexp2(sB[par][r] + bia));
            }
            __builtin_amdgcn_s_setprio(1);
#pragma unroll
            for (int g2 = 0; g2 < 4; g2++)
                oB[g2] = __builtin_amdgcn_mfma_f32_16x16x32_bf16(pfB, vf[g2], oB[g2], 0, 0, 0);
            lB = __builtin_amdgcn_mfma_f32_16x16x32_bf16(pfB, ones, lB, 0, 0, 0);
            __builtin_amdgcn_s_setprio(0);
        }
    }

#pragma unroll
    for (int grp = 0; grp < 2; grp++) {
        int rbase = mt * RT_ + w * 32 + grp * 16 + quad * 4;
        const f32x4* oX = grp ? oB : oA;
        const f32x4& lX = grp ? lB : lA;
#pragma unroll
        for (int reg = 0; reg < 4; reg++) {
            int r = rbase + reg;
            if (r < N_) {
                float inv = 1.0f / lX[reg];
                unsigned short* orow = ob + ((size_t)b * N_ + r) * C_ + h * HD_ + l16;
#pragma unroll
                for (int g2 = 0; g2 < 4; g2++)
                    orow[g2 * 16] = bf16u(oX[g2][reg] * inv);
            }
        }
    }
}

// ---------------------------------------------------------------------------
extern "C" void kernel_launch(void* const* d_in, const int* in_sizes, int n_in,
                              void* d_out, int out_size, void* d_ws, size_t ws_size,
                              hipStream_t stream) {
    const float* x      = (const float*)d_in[0];
    const float* qkv_w  = (const float*)d_in[1];
    const float* proj_w = (const float*)d_in[2];
    const float* proj_b = (const float*)d_in[3];
    const float* wg_w   = (const float*)d_in[4];
    const float* wg_b   = (const float*)d_in[5];
    float* out = (float*)d_out;

    const size_t per = PER_;
    char* ws = (char*)d_ws;
    unsigned short* bigtab = (unsigned short*)ws;                   // 19,464,192 B
    unsigned short* qb     = bigtab + (size_t)8 * 1152 * BW_;       //  8,396,800 B
    unsigned short* kb     = qb + per;                              //  8,396,800 B
    unsigned short* vtc    = kb + per;                              // 11,796,480 B
    unsigned short* ob     = vtc + (size_t)64 * VST * VCS;          //  8,396,800 B

    gemm_qkv_mfma<<<EXP_BLKS + 12 * 65, 256, 0, stream>>>(
        x, qkv_w, wg_w, wg_b, qb, kb, vtc, bigtab);
    attn_fused<<<256, 576, 0, stream>>>(qb, kb, vtc, bigtab, ob);
    gemm_proj_mfma<<<260, 256, 0, stream>>>(ob, proj_w, proj_b, out);
}

// Round 9
// 174.747 us; speedup vs baseline: 1.1337x; 1.0242x over previous
//
#include <hip/hip_runtime.h>
#include <hip/hip_bf16.h>
#include <hip/hip_fp16.h>
#include <math.h>

#define B_  8
#define N_  1025
#define C_  512
#define H_  8
#define HD_ 64
#define M_  (B_ * N_)   // 8200
#define VCS 2560        // shorts per vtc chunk-block: 64 dims * 40 (32 keys + 8 pad)
#define VST 36          // vtc chunk-blocks per bh (33 used)
#define BW_ 1056        // bigtab cols (11 x 96-key tiles)
#define PER_ ((size_t)B_ * H_ * N_ * HD_)      // 4,198,400
#define EXP_BLKS 256
#define GK 512

typedef __attribute__((ext_vector_type(8))) short short8;
typedef __attribute__((ext_vector_type(4))) float f32x4;
typedef __attribute__((ext_vector_type(4))) unsigned short us4;

__device__ inline unsigned short bf16u(float x) {
    __hip_bfloat16 t = __float2bfloat16(x);
    return *(unsigned short*)&t;
}
__device__ inline float fexp2(float x) {   // 2^x via v_exp_f32
    float r;
    asm("v_exp_f32 %0, %1" : "=v"(r) : "v"(x));
    return r;
}
__device__ inline float h2f(unsigned short u) {
    __half_raw hr; hr.x = u;
    return __half2float(__half(hr));
}
__device__ inline void load_lds16(const void* g, void* l) {
    __builtin_amdgcn_global_load_lds(
        (const __attribute__((address_space(1))) unsigned int*)g,
        (__attribute__((address_space(3))) unsigned int*)l, 16, 0, 0);
}
__device__ inline short8 pack8(float4 u0, float4 u1) {
    short8 r;
    r[0] = (short)bf16u(u0.x); r[1] = (short)bf16u(u0.y);
    r[2] = (short)bf16u(u0.z); r[3] = (short)bf16u(u0.w);
    r[4] = (short)bf16u(u1.x); r[5] = (short)bf16u(u1.y);
    r[6] = (short)bf16u(u1.z); r[7] = (short)bf16u(u1.w);
    return r;
}

struct TileRegs { float4 a0, a1, a2, a3, b0, b1, b2, b3; };

// ---------------------------------------------------------------------------
// GEMM QKV + bigtab, ONE dispatch (UNCHANGED from R8 — the 53-57 µs anchor).
// ---------------------------------------------------------------------------
__global__ __launch_bounds__(256) void gemm_qkv_mfma(
        const float* __restrict__ x, const float* __restrict__ qkv_w,
        const float* __restrict__ wg_w, const float* __restrict__ wg_b,
        unsigned short* __restrict__ qb, unsigned short* __restrict__ kb,
        unsigned short* __restrict__ vtc, unsigned short* __restrict__ big) {
    __shared__ __align__(16) unsigned short As[2][4096];
    __shared__ __align__(16) unsigned short Bs[2][4096];
    int lin = blockIdx.x;
    int tid = threadIdx.x;

    if (lin < EXP_BLKS) {
        float* tl = (float*)&As[0][0];          // 4 KB of the 16 KB As
        float* sT = (float*)&Bs[0][0];
        float* cT = sT + 256;
        int h = lin >> 5, rs = lin & 31;
        const float* w = wg_w + h * 64;
        {
            const float fr[8] = {1.0f, 0.421696503f, 0.177827941f, 0.074989421f,
                                 0.031622777f, 0.013335214f, 0.005623413f, 0.002371374f};
            int a = tid >> 3, k = tid & 7;
            float dxv = logf(fmaxf((float)a * (1.0f / 33.0f), 0.001f));
            float ang = 100.0f * dxv * fr[k];
            sT[tid] = sinf(ang);
            cT[tid] = cosf(ang);
        }
        __syncthreads();
        float wb = wg_b[h];
        float wtail = 0.f;
#pragma unroll
        for (int k = 0; k < 8; k++) wtail += w[48 + k] + w[56 + k];
#pragma unroll 1
        for (int e = tid; e < 1024; e += 256) {
            int a = e >> 5, b = e & 31;
            float acc = wb + wtail;
#pragma unroll
            for (int k = 0; k < 8; k++) {
                acc += w[k]      * sT[a * 8 + k];
                acc += w[8 + k]  * sT[b * 8 + k];
                acc += w[32 + k] * cT[a * 8 + k];
                acc += w[40 + k] * cT[b * 8 + k];
            }
            tl[e] = log2f(fmaxf(fmaxf(acc, 0.0f), 1e-6f));
        }
        __syncthreads();
        int rbase = rs * 36;
#pragma unroll 1
        for (int e8 = tid; e8 < 36 * 132; e8 += 256) {
            int rr = e8 / 132;
            int cg = e8 - rr * 132;
            int r = rbase + rr;
            int c0 = cg * 8;
            int i = min(r, 1024) - 1;
            int ix = i >> 5, iy = i & 31;
            unsigned short o8[8];
#pragma unroll
            for (int e = 0; e < 8; e++) {
                int c = c0 + e;
                float v;
                if (r == 0 || c == 0) v = 0.f;
                else if (c > 1024)    v = -60000.f;
                else {
                    int j = c - 1;
                    int da = __sad(ix, j >> 5, 0u);
                    int db = __sad(iy, j & 31, 0u);
                    v = tl[da * 32 + db];
                }
                __half hv = __float2half(v);
                o8[e] = *(unsigned short*)&hv;
            }
            *(short8*)(big + ((size_t)h * 1152 + r) * BW_ + c0) = *(short8*)o8;
        }
        return;
    }

    // bijective XCD swizzle: 780 blocks = 8*97+4 (m204). orig%8 = HW XCD.
    int orig = lin - EXP_BLKS;
    int xcd = orig & 7, pos = orig >> 3;
    int wgid = (xcd < 4) ? xcd * 98 + pos : 392 + (xcd - 4) * 97 + pos;
    int bx = wgid % 12, by = wgid / 12;        // bx fastest: A-tile reused 12x in-XCD

    int wv = tid >> 6, lane = tid & 63;
    int quad = lane >> 4, l16 = lane & 15;
    int m0 = by * 128, n0 = bx * 128;
    int wr = (wv >> 1) * 64, wc = (wv & 1) * 64;

    int ar0 = min(m0 + (tid >> 2), M_ - 1);
    int ar1 = min(m0 + 64 + (tid >> 2), M_ - 1);
    int br0 = n0 + (tid >> 2), br1 = n0 + 64 + (tid >> 2);
    int ac = (tid & 3) * 8;

    int which = n0 >> 9;                       // 0=q 1=k 2=v
    int h = ((n0 + wc) >> 6) & 7;

    f32x4 acc[4][4];
    const f32x4 zero4 = {0.f, 0.f, 0.f, 0.f};
#pragma unroll
    for (int mi = 0; mi < 4; mi++)
#pragma unroll
        for (int ni = 0; ni < 4; ni++) acc[mi][ni] = zero4;

    auto loadT = [&](int t, TileRegs& r) {
        int k0 = t * 32;
        const float* pa0 = x + (size_t)ar0 * GK + k0 + ac;
        const float* pa1 = x + (size_t)ar1 * GK + k0 + ac;
        const float* pb0 = qkv_w + (size_t)br0 * GK + k0 + ac;
        const float* pb1 = qkv_w + (size_t)br1 * GK + k0 + ac;
        r.a0 = *(const float4*)pa0; r.a1 = *(const float4*)(pa0 + 4);
        r.a2 = *(const float4*)pa1; r.a3 = *(const float4*)(pa1 + 4);
        r.b0 = *(const float4*)pb0; r.b1 = *(const float4*)(pb0 + 4);
        r.b2 = *(const float4*)pb1; r.b3 = *(const float4*)(pb1 + 4);
    };
    int wrow = tid >> 2;                        // 0..63
    int wg = ((tid & 3) ^ (wrow >> 1)) & 3;     // granule swizzle (write side)
    auto writeT = [&](const TileRegs& r, int buf) {
        *(short8*)&As[buf][wrow * 32 + wg * 8]        = pack8(r.a0, r.a1);
        *(short8*)&As[buf][(wrow + 64) * 32 + wg * 8] = pack8(r.a2, r.a3);
        *(short8*)&Bs[buf][wrow * 32 + wg * 8]        = pack8(r.b0, r.b1);
        *(short8*)&Bs[buf][(wrow + 64) * 32 + wg * 8] = pack8(r.b2, r.b3);
    };
    auto compute = [&](int buf) {
        short8 af[4], bf[4];
#pragma unroll
        for (int mi = 0; mi < 4; mi++) {
            int rr = wr + mi * 16 + l16;
            af[mi] = *(const short8*)&As[buf][rr * 32 + ((quad ^ (rr >> 1)) & 3) * 8];
        }
#pragma unroll
        for (int ni = 0; ni < 4; ni++) {
            int rr = wc + ni * 16 + l16;
            bf[ni] = *(const short8*)&Bs[buf][rr * 32 + ((quad ^ (rr >> 1)) & 3) * 8];
        }
#pragma unroll
        for (int mi = 0; mi < 4; mi++)
#pragma unroll
            for (int ni = 0; ni < 4; ni++)
                acc[mi][ni] = __builtin_amdgcn_mfma_f32_16x16x32_bf16(
                    bf[ni], af[mi], acc[mi][ni], 0, 0, 0);
    };

    TileRegs tA, tB;
    loadT(0, tA);
    writeT(tA, 0);          // vmcnt wait on tA here (prologue only)
    loadT(1, tB);

#pragma unroll 1
    for (int kk = 0; kk < 16; kk += 2) {
        __syncthreads();                 // newest outstanding load is 1 step old
        if (kk + 2 < 16) loadT(kk + 2, tA);
        compute(0);
        if (kk + 1 < 16) writeT(tB, 1);  // tB in flight a full step: covered
        __syncthreads();
        if (kk + 3 < 16) loadT(kk + 3, tB);
        compute(1);
        if (kk + 2 < 16) writeT(tA, 0);
    }

    if (which < 2) {
        unsigned short* dst = (which == 0) ? qb : kb;
        float sc = (which == 0) ? 0.18033688f : 1.0f;   // 0.125 * log2(e)
#pragma unroll
        for (int mi = 0; mi < 4; mi++) {
            int m = m0 + wr + mi * 16 + l16;
            if (m < M_) {
                int bb = m / N_;
                int i  = m - bb * N_;
                unsigned short* row = dst + ((size_t)(bb * H_ + h) * N_ + i) * HD_;
#pragma unroll
                for (int ni = 0; ni < 4; ni++) {
                    ushort4 pk;
                    pk.x = bf16u(acc[mi][ni][0] * sc);
                    pk.y = bf16u(acc[mi][ni][1] * sc);
                    pk.z = bf16u(acc[mi][ni][2] * sc);
                    pk.w = bf16u(acc[mi][ni][3] * sc);
                    *(ushort4*)(row + ni * 16 + quad * 4) = pk;
                }
            }
        }
    } else {
#pragma unroll
        for (int mi = 0; mi < 4; mi++) {
            int m = m0 + wr + mi * 16 + l16;
            if (m < M_) {
                int bb = m / N_;
                int i  = m - bb * N_;
                int ch = i >> 5, key = i & 31;
                int slot = ((key >> 2) & 3) * 8 + ((key >> 4) << 2) + (key & 3);
                unsigned short* base = vtc + ((size_t)(bb * H_ + h) * VST + ch) * VCS + slot;
#pragma unroll
                for (int ni = 0; ni < 4; ni++)
#pragma unroll
                    for (int reg = 0; reg < 4; reg++)
                        base[(ni * 16 + quad * 4 + reg) * 40] = bf16u(acc[mi][ni][reg]);
            }
        }
    }
}

// ---------------------------------------------------------------------------
// GEMM proj v2: R8 accounting shows proj ~45-52 µs at 260 blocks = 1 block/CU
// = 4 waves/CU -> a single barrier-locked block per CU with no TLP to hide
// load latency (same disease R5 attn had). Now 128x64 tiles, grid 520 = 8 n x
// 65 m -> 2 blocks/CU, 8 waves/CU; acc shrinks to 8 f32x4 (VGPR ~64). Contig
// bijective XCD map (520 = 8*65): each XCD owns an m-band (A-rows L2-local).
// A-side global_load_lds (pre-swizzled col); W-side f32 reg-staged distance-2.
// LDS 24 KB/block.
// ---------------------------------------------------------------------------
struct WRegs { float4 w0, w1; };

__global__ __launch_bounds__(256) void gemm_proj_mfma(
        const unsigned short* __restrict__ A, const float* __restrict__ Wf,
        const float* __restrict__ bias, float* __restrict__ out) {
    __shared__ __align__(16) unsigned short As[2][4096];
    __shared__ __align__(16) unsigned short Bs[2][2048];
    int tid = threadIdx.x;
    int w = tid >> 6, lane = tid & 63;
    int quad = lane >> 4, l16 = lane & 15;

    int orig = blockIdx.x;                     // 520 = 8 * 65
    int wgid = (orig & 7) * 65 + (orig >> 3);  // XCD-contiguous m-bands
    int bn = wgid & 7, bm = wgid >> 3;

    int m0 = bm * 128;
    int n0 = bn * 64;
    int wr = (w >> 1) * 64, wc = (w & 1) * 32;

    int ar0 = min(m0 + (tid >> 2), M_ - 1);
    int ar1 = min(m0 + 64 + (tid >> 2), M_ - 1);
    int brW = n0 + (tid >> 2);                 // 0..511, no clamp needed
    int acW = (tid & 3) * 8;
    int acA = (((tid & 3) ^ ((tid >> 3) & 3))) * 8;   // pre-swizzled global col

    f32x4 acc[4][2];
    const f32x4 zero4 = {0.f, 0.f, 0.f, 0.f};
#pragma unroll
    for (int mi = 0; mi < 4; mi++)
#pragma unroll
        for (int ni = 0; ni < 2; ni++) acc[mi][ni] = zero4;

    auto stageA = [&](int t, int buf) {
        int k0 = t * 32;
        load_lds16(A + (size_t)ar0 * GK + k0 + acA, &As[buf][w * 512]);
        load_lds16(A + (size_t)ar1 * GK + k0 + acA, &As[buf][2048 + w * 512]);
    };
    auto loadW = [&](int t, WRegs& r) {
        int k0 = t * 32;
        const float* p0 = Wf + (size_t)brW * GK + k0 + acW;
        r.w0 = *(const float4*)p0; r.w1 = *(const float4*)(p0 + 4);
    };
    int wrow = tid >> 2;
    int wg = ((tid & 3) ^ (wrow >> 1)) & 3;
    auto writeW = [&](const WRegs& r, int buf) {
        *(short8*)&Bs[buf][wrow * 32 + wg * 8] = pack8(r.w0, r.w1);
    };
    auto compute = [&](int buf) {
        short8 af[4], bf[2];
#pragma unroll
        for (int mi = 0; mi < 4; mi++) {
            int rr = wr + mi * 16 + l16;
            af[mi] = *(const short8*)&As[buf][rr * 32 + ((quad ^ (rr >> 1)) & 3) * 8];
        }
#pragma unroll
        for (int ni = 0; ni < 2; ni++) {
            int rr = wc + ni * 16 + l16;
            bf[ni] = *(const short8*)&Bs[buf][rr * 32 + ((quad ^ (rr >> 1)) & 3) * 8];
        }
#pragma unroll
        for (int mi = 0; mi < 4; mi++)
#pragma unroll
            for (int ni = 0; ni < 2; ni++)
                acc[mi][ni] = __builtin_amdgcn_mfma_f32_16x16x32_bf16(
                    af[mi], bf[ni], acc[mi][ni], 0, 0, 0);
    };

    WRegs tA, tB;
    stageA(0, 0);
    loadW(0, tA);
    writeW(tA, 0);
    loadW(1, tB);

#pragma unroll 1
    for (int kk = 0; kk < 16; kk += 2) {
        __syncthreads();
        if (kk + 1 < 16) stageA(kk + 1, 1);
        if (kk + 2 < 16) loadW(kk + 2, tA);
        compute(0);
        if (kk + 1 < 16) writeW(tB, 1);
        __syncthreads();
        if (kk + 2 < 16) stageA(kk + 2, 0);
        if (kk + 3 < 16) loadW(kk + 3, tB);
        compute(1);
        if (kk + 2 < 16) writeW(tA, 0);
    }

    float bvals[2];
#pragma unroll
    for (int ni = 0; ni < 2; ni++) bvals[ni] = bias[n0 + wc + ni * 16 + l16];
#pragma unroll
    for (int mi = 0; mi < 4; mi++)
#pragma unroll
        for (int reg = 0; reg < 4; reg++) {
            int m = m0 + wr + mi * 16 + quad * 4 + reg;
            if (m < M_) {
                float* row = out + (size_t)m * C_ + n0 + wc;
#pragma unroll
                for (int ni = 0; ni < 2; ni++)
                    row[ni * 16 + l16] = acc[mi][ni][reg] + bvals[ni];
            }
        }
}

// ---------------------------------------------------------------------------
// FUSED attention v8 (UNCHANGED — the 47.2 µs anchor):
// 32 query rows per wave (two l16-groups sharing every K/V ds_read), grid
// 256 = 64 bh x 4 mt, blockIdx%8 = h for XCD L2 co-location. Swapped-QK
// registers-only softmax; bias A prefetched one tile ahead, B in-tile.
// ---------------------------------------------------------------------------
#define RT_ 288   // rows per block (9 waves x 32)

__global__ __launch_bounds__(576, 3) void attn_fused(
        const unsigned short* __restrict__ qg,
        const unsigned short* __restrict__ kg,
        const unsigned short* __restrict__ vtc,
        const unsigned short* __restrict__ bigtab,
        unsigned short* __restrict__ ob) {
    __shared__ __align__(16) unsigned short Ks[2][6144];   // 24 KB
    __shared__ __align__(16) unsigned short Vs[2][7680];   // 30 KB

    int tid = threadIdx.x;
    int w = tid >> 6, lane = tid & 63;
    int quad = lane >> 4, l16 = lane & 15;

    int lin = blockIdx.x;            // 256 blocks
    int bh = lin & 63;               // blockIdx%8 = bh&7 = h -> XCD co-location
    int mt = lin >> 6;               // 0..3
    int b = bh >> 3, h = bh & 7;

    const unsigned short* qp = qg + (size_t)bh * N_ * HD_;
    const unsigned short* kp = kg + (size_t)bh * N_ * HD_;
    const unsigned short* vp = vtc + (size_t)bh * VST * VCS;

    int qrA = mt * RT_ + w * 32 + l16;           // qgrp A rows (A-layout, l16)
    const unsigned short* btA = bigtab + ((size_t)h * 1152 + qrA) * BW_ + quad * 4;
    const unsigned short* btB = btA + (size_t)16 * BW_;

    short8 qfA[2], qfB[2];
    {
        int rowA = min(qrA, N_ - 1);
        int rowB = min(qrA + 16, N_ - 1);
        qfA[0] = *(const short8*)(qp + (size_t)rowA * HD_ + quad * 8);
        qfA[1] = *(const short8*)(qp + (size_t)rowA * HD_ + 32 + quad * 8);
        qfB[0] = *(const short8*)(qp + (size_t)rowB * HD_ + quad * 8);
        qfB[1] = *(const short8*)(qp + (size_t)rowB * HD_ + 32 + quad * 8);
    }

    f32x4 oA[4], oB[4], lA, lB;
    const f32x4 zero4 = {0.f, 0.f, 0.f, 0.f};
#pragma unroll
    for (int g2 = 0; g2 < 4; g2++) { oA[g2] = zero4; oB[g2] = zero4; }
    lA = zero4; lB = zero4;
    short8 ones;
    {
        short one_bf = (short)0x3F80;
#pragma unroll
        for (int j = 0; j < 8; j++) ones[j] = one_bf;
    }

    // balanced staging: 27 64-chunk blocks (12 K + 15 V), 3 per wave.
    auto stage = [&](int t, int buf) {
#pragma unroll
        for (int r2 = 0; r2 < 3; r2++) {
            int cb = w * 3 + r2;                 // 0..26, uniform per wave
            if (cb < 12) {
                int ch = cb * 64 + lane;
                int ct = ch >> 7, rem = ch & 127;
                int oct = rem >> 4, k16 = rem & 15;
                int key = min(t * 96 + ct * 16 + k16, N_ - 1);
                load_lds16(kp + (size_t)key * HD_ + oct * 8, &Ks[buf][cb * 512]);
            } else {
                int vb = cb - 12;
                load_lds16(vp + (size_t)t * 3 * VCS + (size_t)(vb * 64 + lane) * 8,
                           &Vs[buf][vb * 512]);
            }
        }
    };

    us4 bAc[6], bAn[6];
#pragma unroll
    for (int i = 0; i < 6; i++)
        bAn[i] = *(const us4*)(btA + (i >> 1) * 32 + (i & 1) * 16);
    stage(0, 0);

#pragma unroll 1
    for (int t = 0; t < 11; t++) {
        int buf = t & 1;
        __syncthreads();                  // Ks/Vs[buf] ready (vmcnt drained)

#pragma unroll
        for (int i = 0; i < 6; i++) bAc[i] = bAn[i];
        us4 bB[6];
        {
            const unsigned short* btp = btB + t * 96;
#pragma unroll
            for (int i = 0; i < 6; i++)
                bB[i] = *(const us4*)(btp + (i >> 1) * 32 + (i & 1) * 16);
        }
        if (t < 10) {
            const unsigned short* btp = btA + (t + 1) * 96;
#pragma unroll
            for (int i = 0; i < 6; i++)
                bAn[i] = *(const us4*)(btp + (i >> 1) * 32 + (i & 1) * 16);
            stage(t + 1, buf ^ 1);
        }

#pragma unroll
        for (int ks = 0; ks < 3; ks++) {
            f32x4 sA[2], sB[2];
#pragma unroll
            for (int ctl = 0; ctl < 2; ctl++) {
                int ct = ks * 2 + ctl;
                short8 kf0 = *(const short8*)&Ks[buf][(ct * 128 + quad * 16 + l16) * 8];
                short8 kf1 = *(const short8*)&Ks[buf][(ct * 128 + (4 + quad) * 16 + l16) * 8];
                sA[ctl] = __builtin_amdgcn_mfma_f32_16x16x32_bf16(kf0, qfA[0], zero4, 0, 0, 0);
                sA[ctl] = __builtin_amdgcn_mfma_f32_16x16x32_bf16(kf1, qfA[1], sA[ctl], 0, 0, 0);
                sB[ctl] = __builtin_amdgcn_mfma_f32_16x16x32_bf16(kf0, qfB[0], zero4, 0, 0, 0);
                sB[ctl] = __builtin_amdgcn_mfma_f32_16x16x32_bf16(kf1, qfB[1], sB[ctl], 0, 0, 0);
            }
            const unsigned short* vcp = &Vs[buf][ks * 2560 + quad * 8];
            short8 vf[4];
#pragma unroll
            for (int g2 = 0; g2 < 4; g2++)
                vf[g2] = *(const short8*)(vcp + (g2 * 16 + l16) * 40);

            short8 pfA;
#pragma unroll
            for (int e = 0; e < 8; e++) {
                int par = e >> 2, r = e & 3;
                float bia = h2f(bAc[ks * 2 + par][r]);
                pfA[e] = (short)bf16u(fexp2(sA[par][r] + bia));
            }
            __builtin_amdgcn_s_setprio(1);
#pragma unroll
            for (int g2 = 0; g2 < 4; g2++)
                oA[g2] = __builtin_amdgcn_mfma_f32_16x16x32_bf16(pfA, vf[g2], oA[g2], 0, 0, 0);
            lA = __builtin_amdgcn_mfma_f32_16x16x32_bf16(pfA, ones, lA, 0, 0, 0);
            __builtin_amdgcn_s_setprio(0);

            short8 pfB;
#pragma unroll
            for (int e = 0; e < 8; e++) {
                int par = e >> 2, r = e & 3;
                float bia = h2f(bB[ks * 2 + par][r]);
                pfB[e] = (short)bf16u(fexp2(sB[par][r] + bia));
            }
            __builtin_amdgcn_s_setprio(1);
#pragma unroll
            for (int g2 = 0; g2 < 4; g2++)
                oB[g2] = __builtin_amdgcn_mfma_f32_16x16x32_bf16(pfB, vf[g2], oB[g2], 0, 0, 0);
            lB = __builtin_amdgcn_mfma_f32_16x16x32_bf16(pfB, ones, lB, 0, 0, 0);
            __builtin_amdgcn_s_setprio(0);
        }
    }

#pragma unroll
    for (int grp = 0; grp < 2; grp++) {
        int rbase = mt * RT_ + w * 32 + grp * 16 + quad * 4;
        const f32x4* oX = grp ? oB : oA;
        const f32x4& lX = grp ? lB : lA;
#pragma unroll
        for (int reg = 0; reg < 4; reg++) {
            int r = rbase + reg;
            if (r < N_) {
                float inv = 1.0f / lX[reg];
                unsigned short* orow = ob + ((size_t)b * N_ + r) * C_ + h * HD_ + l16;
#pragma unroll
                for (int g2 = 0; g2 < 4; g2++)
                    orow[g2 * 16] = bf16u(oX[g2][reg] * inv);
            }
        }
    }
}

// ---------------------------------------------------------------------------
extern "C" void kernel_launch(void* const* d_in, const int* in_sizes, int n_in,
                              void* d_out, int out_size, void* d_ws, size_t ws_size,
                              hipStream_t stream) {
    const float* x      = (const float*)d_in[0];
    const float* qkv_w  = (const float*)d_in[1];
    const float* proj_w = (const float*)d_in[2];
    const float* proj_b = (const float*)d_in[3];
    const float* wg_w   = (const float*)d_in[4];
    const float* wg_b   = (const float*)d_in[5];
    float* out = (float*)d_out;

    const size_t per = PER_;
    char* ws = (char*)d_ws;
    unsigned short* bigtab = (unsigned short*)ws;                   // 19,464,192 B
    unsigned short* qb     = bigtab + (size_t)8 * 1152 * BW_;       //  8,396,800 B
    unsigned short* kb     = qb + per;                              //  8,396,800 B
    unsigned short* vtc    = kb + per;                              // 11,796,480 B
    unsigned short* ob     = vtc + (size_t)64 * VST * VCS;          //  8,396,800 B

    gemm_qkv_mfma<<<EXP_BLKS + 12 * 65, 256, 0, stream>>>(
        x, qkv_w, wg_w, wg_b, qb, kb, vtc, bigtab);
    attn_fused<<<256, 576, 0, stream>>>(qb, kb, vtc, bigtab, ob);
    gemm_proj_mfma<<<520, 256, 0, stream>>>(ob, proj_w, proj_b, out);
}